// Round 7
// baseline (214.223 us; speedup 1.0000x reference)
//
#include <hip/hip_runtime.h>
#include <hip/hip_bf16.h>

#define NN 512
#define EE 8192

// ---- workspace layout (float offsets) ----
#define OFF_F     0u
#define OFF_MTR1  2097152u      // full path: N*N*16 bf16 (mtr1B) ; fallback: fp32 mtr1T
#define OFF_W     6291456u
#define WR_W0   0
#define WR_B0   512
#define WR_W1   576
#define WR_B1   4672
#define WR_W2   4736
#define WR_B2   8832
#define WR_W3   8896
#define WR_B3   25280
#define WR_V0T  25536
#define WR_C0   26560
#define WR_V1   26624
#define WR_C1   30720
#define WR_V2   30784
#define WR_C2   34880
#define WR_V3   34944
#define WR_C3   35968
#define WR_L    35984
#define WR_LB   36240
#define W_TOTAL 36256
#define OFF_OFFS    (OFF_W + W_TOTAL)
#define OFF_SORTED  (OFF_OFFS + 513)
#define OFF_FLAG    (OFF_SORTED + EE)
#define OFF_MTRT    6336420u
#define OFF_OFFSP   8433572u
#define OFF_PACKP   8434085u
#define OFF_FPACK   8442792u
#define OFF_VPACK   9491496u
#define WS_NEED_BYTES  ((size_t)(OFF_MTRT  + 2097152u) * 4u)
#define WS_FULL2_BYTES ((size_t)(OFF_VPACK + 5632u) * 4u)

#define VP0OFF 0
#define VP1OFF 2048
#define VP2OFF 6144
#define VP3OFF 10240

#define XS   64   // XB row stride (bf16 units) = 128 B; 256 rows = 32768 B
#define RSTR 20   // RRB row stride, f32

typedef __attribute__((ext_vector_type(8))) short bf16x8;
typedef __attribute__((ext_vector_type(4))) float f32x4;

__device__ __forceinline__ float bflo(unsigned u){ return __uint_as_float(u << 16); }
__device__ __forceinline__ float bfhi(unsigned u){ return __uint_as_float(u & 0xffff0000u); }
__device__ __forceinline__ unsigned short f2bf(float f){
  __hip_bfloat16 h = __float2bfloat16(f);
  union { __hip_bfloat16 hh; unsigned short ss; } u;
  u.hh = h; return u.ss;
}
__device__ __forceinline__ unsigned pack2(float a, float b){
  return (unsigned)f2bf(a) | ((unsigned)f2bf(b) << 16);
}
__device__ __forceinline__ float cvt(float v){ return v; }
__device__ __forceinline__ float cvt(__hip_bfloat16 v){ return __bfloat162float(v); }

__device__ __forceinline__ void load16f(const void* base, size_t eoff, int f32, float m[16]) {
  if (f32) {
    const float4* p = (const float4*)((const float*)base + eoff);
    float4 a = p[0], b = p[1], c = p[2], d = p[3];
    m[0]=a.x; m[1]=a.y; m[2]=a.z; m[3]=a.w;
    m[4]=b.x; m[5]=b.y; m[6]=b.z; m[7]=b.w;
    m[8]=c.x; m[9]=c.y; m[10]=c.z; m[11]=c.w;
    m[12]=d.x; m[13]=d.y; m[14]=d.z; m[15]=d.w;
  } else {
    const uint4* p = (const uint4*)((const __hip_bfloat16*)base + eoff);
    uint4 u0 = p[0], u1 = p[1];
    m[0]=bflo(u0.x);  m[1]=bfhi(u0.x);  m[2]=bflo(u0.y);  m[3]=bfhi(u0.y);
    m[4]=bflo(u0.z);  m[5]=bfhi(u0.z);  m[6]=bflo(u0.w);  m[7]=bfhi(u0.w);
    m[8]=bflo(u1.x);  m[9]=bfhi(u1.x);  m[10]=bflo(u1.y); m[11]=bfhi(u1.y);
    m[12]=bflo(u1.z); m[13]=bfhi(u1.z); m[14]=bflo(u1.w); m[15]=bfhi(u1.w);
  }
}

__device__ __forceinline__ float ldelem(const void* p, int idx, int f32) {
  return f32 ? ((const float*)p)[idx]
             : __bfloat162float(((const __hip_bfloat16*)p)[idx]);
}

__device__ __forceinline__ int detect_f32_local(const unsigned short* mtr_u16, float* red) {
  int tid = threadIdx.x;
  float m = 0.f;
  for (int t = tid; t < 4096; t += 512) {
    float v = __uint_as_float(((unsigned)mtr_u16[t]) << 16);
    if (v != v) m = 3e38f;
    else m = fmaxf(m, fabsf(v));
  }
  red[tid] = m;
  __syncthreads();
  for (int s = 256; s > 0; s >>= 1) {
    if (tid < s) red[tid] = fmaxf(red[tid], red[tid + s]);
    __syncthreads();
  }
  float mx = red[0];
  __syncthreads();
  return (mx > 1e6f) ? 1 : 0;
}

template <typename T>
__device__ void edge_body(const T* __restrict__ ea,
                          const T* __restrict__ W0, const T* __restrict__ b0,
                          const T* __restrict__ W1, const T* __restrict__ b1,
                          const T* __restrict__ W2, const T* __restrict__ b2,
                          const T* __restrict__ W3, const T* __restrict__ b3,
                          int e, int eg, int lane,
                          float (*shA)[64], float (*shB)[64],
                          unsigned short* __restrict__ Fpack)
{
  float x[8];
  #pragma unroll
  for (int c = 0; c < 8; c++) x[c] = cvt(ea[(size_t)e * 8 + c]);

  float s = cvt(b0[lane]);
  #pragma unroll
  for (int c = 0; c < 8; c++) s += x[c] * cvt(W0[c * 64 + lane]);
  shA[eg][lane] = fmaxf(s, 0.f);
  __syncthreads();

  s = cvt(b1[lane]);
  #pragma unroll
  for (int c = 0; c < 64; c++) s += shA[eg][c] * cvt(W1[c * 64 + lane]);
  shB[eg][lane] = fmaxf(s, 0.f);
  __syncthreads();

  s = cvt(b2[lane]);
  #pragma unroll
  for (int c = 0; c < 64; c++) s += shB[eg][c] * cvt(W2[c * 64 + lane]);
  shA[eg][lane] = fmaxf(s, 0.f);
  __syncthreads();

  int quad = lane >> 4, tt = lane & 15;
  #pragma unroll
  for (int r = 0; r < 4; r++) {
    int o = r * 64 + lane;
    float t = cvt(b3[o]);
    #pragma unroll
    for (int c = 0; c < 64; c++) t += shA[eg][c] * cvt(W3[c * 256 + o]);
    int cc = r * 4 + quad;
    Fpack[(size_t)e * 256 + (cc >> 3) * 128 + tt * 8 + (cc & 7)] = f2bf(t);
  }
}

// ---- K1: fused prep (roles by blockIdx.x) ----
__global__ __launch_bounds__(512) void prep_all(
  const void* __restrict__ mtr, const void* __restrict__ ea, const int* __restrict__ ei,
  const void* __restrict__ W0, const void* __restrict__ b0,
  const void* __restrict__ W1, const void* __restrict__ b1,
  const void* __restrict__ W2, const void* __restrict__ b2,
  const void* __restrict__ W3, const void* __restrict__ b3,
  const void* __restrict__ V0, const void* __restrict__ c0,
  const void* __restrict__ V1, const void* __restrict__ c1,
  const void* __restrict__ V2, const void* __restrict__ c2,
  const void* __restrict__ V3, const void* __restrict__ c3,
  const void* __restrict__ L,  const void* __restrict__ Lb,
  int* __restrict__ flag, float* __restrict__ w, unsigned short* __restrict__ VP,
  int* __restrict__ offsP, unsigned* __restrict__ packP,
  unsigned short* __restrict__ Fpack, __hip_bfloat16* __restrict__ mtrT)
{
  __shared__ __attribute__((aligned(16))) char smem_raw[8192];
  int tid = threadIdx.x;
  int bid = blockIdx.x;
  const int f32 = detect_f32_local((const unsigned short*)mtr, (float*)smem_raw);

  if (bid == 0) {
    int* cnt  = (int*)smem_raw;
    int* pcs  = cnt + 512;
    int* curP = pcs + 512;
    cnt[tid] = 0;
    if (tid == 0) flag[0] = f32;
    __syncthreads();
    for (int e = tid; e < EE; e += 512) atomicAdd(&cnt[ei[EE + e]], 1);
    __syncthreads();
    int myc = cnt[tid];
    int myp = (myc + 1) & ~1;
    pcs[tid] = myp;
    __syncthreads();
    for (int off = 1; off < 512; off <<= 1) {
      int b = (tid >= off) ? pcs[tid - off] : 0;
      __syncthreads();
      pcs[tid] += b;
      __syncthreads();
    }
    int excP = pcs[tid] - myp;
    offsP[tid] = excP;
    if (tid == 511) offsP[512] = pcs[511];
    curP[tid] = excP;
    if (myc & 1) packP[excP + myc] = EE;
    __syncthreads();
    for (int e = tid; e < EE; e += 512) {
      int d = ei[EE + e];
      int s = ei[e];
      packP[atomicAdd(&curP[d], 1)] = (unsigned)e | ((unsigned)s << 14);
    }
    unsigned* fz = (unsigned*)(Fpack + (size_t)EE * 256);
    for (int i2 = tid; i2 < 128; i2 += 512) fz[i2] = 0u;
  } else if (bid < 33) {
    int g = (bid - 1) * 512 + tid;
    const int stride = 32 * 512;
    auto cv = [&](const void* p, int off, int n){
      for (int i = g; i < n; i += stride) w[off + i] = ldelem(p, i, f32);
    };
    cv(W0, WR_W0, 512);  cv(b0, WR_B0, 64);
    cv(W1, WR_W1, 4096); cv(b1, WR_B1, 64);
    cv(W2, WR_W2, 4096); cv(b2, WR_B2, 64);
    cv(W3, WR_W3, 16384);cv(b3, WR_B3, 256);
    for (int idx = g; idx < 1024; idx += stride) {
      int j = idx >> 4, t = idx & 15;
      w[WR_V0T + idx] = ldelem(V0, t * 64 + j, f32);
    }
    cv(c0, WR_C0, 64);
    cv(V1, WR_V1, 4096); cv(c1, WR_C1, 64);
    cv(V2, WR_V2, 4096); cv(c2, WR_C2, 64);
    cv(V3, WR_V3, 1024); cv(c3, WR_C3, 16);
    cv(L,  WR_L,  256);  cv(Lb, WR_LB, 16);
  } else if (bid < 37) {
    int g = (bid - 33) * 512 + tid;
    const int stride = 4 * 512;
    for (int idx = g; idx < 2048; idx += stride) {
      int j = idx & 7, lp = (idx >> 3) & 63, nt = idx >> 9;
      int nn = lp & 15, qq = lp >> 4;
      int kk = qq * 8 + j;
      float v = (kk < 16) ? ldelem(V0, kk * 64 + nt * 16 + nn, f32) : 0.f;
      VP[VP0OFF + idx] = f2bf(v);
    }
    for (int idx = g; idx < 4096; idx += stride) {
      int j = idx & 7, lp = (idx >> 3) & 63, tile = idx >> 9;
      int nn = lp & 15, qq = lp >> 4;
      int kc = tile >> 2, nt = tile & 3;
      int kk = kc * 32 + qq * 8 + j;
      VP[VP1OFF + idx] = f2bf(ldelem(V1, kk * 64 + nt * 16 + nn, f32));
      VP[VP2OFF + idx] = f2bf(ldelem(V2, kk * 64 + nt * 16 + nn, f32));
    }
    for (int idx = g; idx < 1024; idx += stride) {
      int j = idx & 7, lp = (idx >> 3) & 63, kc = idx >> 9;
      int nn = lp & 15, qq = lp >> 4;
      int kk = kc * 32 + qq * 8 + j;
      VP[VP3OFF + idx] = f2bf(ldelem(V3, kk * 16 + nn, f32));
    }
  } else if (bid < 549) {
    int s = bid - 37;
    int i = tid;
    float m[16];
    load16f(mtr, (size_t)i * 8192 + (size_t)s * 16, f32, m);
    unsigned pw[8];
    #pragma unroll
    for (int q = 0; q < 8; q++) pw[q] = pack2(m[2*q], m[2*q+1]);
    uint4* op = (uint4*)(mtrT + (size_t)s * 8192 + (size_t)i * 16);
    op[0] = make_uint4(pw[0], pw[1], pw[2], pw[3]);
    op[1] = make_uint4(pw[4], pw[5], pw[6], pw[7]);
  } else {
    int eg = tid >> 6, lane = tid & 63;
    int e = (bid - 549) * 8 + eg;
    float (*shA)[64] = (float(*)[64])smem_raw;
    float (*shB)[64] = (float(*)[64])(smem_raw + 2048);
    if (f32)
      edge_body<float>((const float*)ea,
        (const float*)W0, (const float*)b0, (const float*)W1, (const float*)b1,
        (const float*)W2, (const float*)b2, (const float*)W3, (const float*)b3,
        e, eg, lane, shA, shB, Fpack);
    else
      edge_body<__hip_bfloat16>((const __hip_bfloat16*)ea,
        (const __hip_bfloat16*)W0, (const __hip_bfloat16*)b0,
        (const __hip_bfloat16*)W1, (const __hip_bfloat16*)b1,
        (const __hip_bfloat16*)W2, (const __hip_bfloat16*)b2,
        (const __hip_bfloat16*)W3, (const __hip_bfloat16*)b3,
        e, eg, lane, shA, shB, Fpack);
  }
}

// ---- K2: message via MFMA; grid (512 k, 4 i-quarters); bf16 mtr1 output ----
__global__ __launch_bounds__(256) void message_mfma2(
  const __hip_bfloat16* __restrict__ mtrT,
  const unsigned short* __restrict__ Fpack,
  const int* __restrict__ offsP, const unsigned* __restrict__ packP,
  __hip_bfloat16* __restrict__ mtr1B)
{
  int k = blockIdx.x;
  int tid = threadIdx.x;
  int wave = tid >> 6, lane = tid & 63;
  int n = lane & 15, quad = lane >> 4;
  int qh = quad >> 1, qq = quad & 1;
  int ibase = blockIdx.y * 128 + wave * 32;
  int j0 = offsP[k], j1 = offsP[k + 1];

  f32x4 acc0 = (f32x4){0.f,0.f,0.f,0.f};
  f32x4 acc1 = (f32x4){0.f,0.f,0.f,0.f};

  bf16x8 bfrag, af0, af1;
  auto loadfr = [&](int j) {
    unsigned p1 = __builtin_amdgcn_readfirstlane(packP[j]);
    unsigned p2 = __builtin_amdgcn_readfirstlane(packP[j + 1]);
    unsigned pv = qh ? p2 : p1;
    int es = (int)(pv & 0x3FFFu);
    int ss = (int)(pv >> 14);
    bfrag = *(const bf16x8*)(Fpack + (size_t)es * 256 + (qq * 16 + n) * 8);
    const __hip_bfloat16* ab = mtrT + (size_t)ss * 8192 + qq * 8;
    af0 = *(const bf16x8*)(ab + (size_t)(ibase + 0 * 16 + n) * 16);
    af1 = *(const bf16x8*)(ab + (size_t)(ibase + 1 * 16 + n) * 16);
  };
  if (j0 < j1) loadfr(j0);
  for (int j = j0; j < j1; j += 2) {
    bf16x8 bc = bfrag, a0 = af0, a1 = af1;
    if (j + 2 < j1) loadfr(j + 2);
    acc0 = __builtin_amdgcn_mfma_f32_16x16x32_bf16(a0, bc, acc0, 0, 0, 0);
    acc1 = __builtin_amdgcn_mfma_f32_16x16x32_bf16(a1, bc, acc1, 0, 0, 0);
  }

  __hip_bfloat16* obase = mtr1B + (size_t)k * 8192;
  #pragma unroll
  for (int reg = 0; reg < 4; reg++) {
    int r0 = ibase + 0 * 16 + quad * 4 + reg;
    int r1 = ibase + 1 * 16 + quad * 4 + reg;
    obase[(size_t)r0 * 16 + n] = __float2bfloat16(acc0[reg]);
    obase[(size_t)r1 * 16 + n] = __float2bfloat16(acc1[reg]);
  }
}

// ---- K3: final via MFMA; coalesced LDS tile staging + swizzled 32 KB XB ----
__global__ __launch_bounds__(256, 5) void final_mfma(
  const void* __restrict__ mtr, const float* __restrict__ w,
  const __hip_bfloat16* __restrict__ mtr1B, const int* __restrict__ flag,
  const unsigned short* __restrict__ VP, void* __restrict__ out)
{
  const int f32 = flag[0];
  __shared__ __attribute__((aligned(16))) unsigned short XB[256 * XS];  // 32768 B
  int tid = threadIdx.x;
  int ti = blockIdx.x >> 5, tk = blockIdx.x & 31;
  int i0 = ti * 16, k0 = tk * 16;

  // ---- stage A (rows k0.., cols i0..) and B (rows i0.., cols k0..), coalesced ----
  // row stride 264 bf16 units (528 B); A at 0, B at 4224 units (8448 B)
  {
    int row = tid >> 4, off = tid & 15;
    const uint4* ga = (const uint4*)(mtr1B + (size_t)(k0 + row) * 8192 + (size_t)i0 * 16);
    const uint4* gb = (const uint4*)(mtr1B + (size_t)(i0 + row) * 8192 + (size_t)k0 * 16);
    uint4* la = (uint4*)(XB + row * 264);
    uint4* lb = (uint4*)(XB + 4224 + row * 264);
    la[off*2]   = ga[off*2];
    la[off*2+1] = ga[off*2+1];
    lb[off*2]   = gb[off*2];
    lb[off*2+1] = gb[off*2+1];
  }
  __syncthreads();

  int r = tid >> 4, c = tid & 15;
  int i = i0 + r, k = k0 + c;
  float scale = (i == k) ? 0.f : 0.0625f;

  float y[16];
  {
    const uint4* ap = (const uint4*)(XB + c * 264 + r * 16);
    const uint4* bp = (const uint4*)(XB + 4224 + r * 264 + c * 16);
    uint4 a0 = ap[0], a1 = ap[1], b0 = bp[0], b1 = bp[1];
    float a_[16], b_[16];
    a_[0]=bflo(a0.x);  a_[1]=bfhi(a0.x);  a_[2]=bflo(a0.y);  a_[3]=bfhi(a0.y);
    a_[4]=bflo(a0.z);  a_[5]=bfhi(a0.z);  a_[6]=bflo(a0.w);  a_[7]=bfhi(a0.w);
    a_[8]=bflo(a1.x);  a_[9]=bfhi(a1.x);  a_[10]=bflo(a1.y); a_[11]=bfhi(a1.y);
    a_[12]=bflo(a1.z); a_[13]=bfhi(a1.z); a_[14]=bflo(a1.w); a_[15]=bfhi(a1.w);
    b_[0]=bflo(b0.x);  b_[1]=bfhi(b0.x);  b_[2]=bflo(b0.y);  b_[3]=bfhi(b0.y);
    b_[4]=bflo(b0.z);  b_[5]=bfhi(b0.z);  b_[6]=bflo(b0.w);  b_[7]=bfhi(b0.w);
    b_[8]=bflo(b1.x);  b_[9]=bfhi(b1.x);  b_[10]=bflo(b1.y); b_[11]=bfhi(b1.y);
    b_[12]=bflo(b1.z); b_[13]=bfhi(b1.z); b_[14]=bflo(b1.w); b_[15]=bfhi(b1.w);
    const float* Lf  = w + WR_L;
    const float* Lbf = w + WR_LB;
    #pragma unroll
    for (int t = 0; t < 16; t++) y[t] = a_[t] * scale + Lbf[t];
    #pragma unroll
    for (int cc = 0; cc < 16; cc++) {
      float bs = b_[cc] * scale;
      #pragma unroll
      for (int t = 0; t < 16; t++) y[t] += bs * Lf[cc * 16 + t];
    }
  }
  __syncthreads();   // tiles dead; region becomes swizzled XB

  // ---- stage y: row=tid, logical 16B-groups g, phys gp = g ^ (row&7) ----
  {
    unsigned sw = tid & 7;
    uint4 d0 = make_uint4(pack2(y[0],y[1]),  pack2(y[2],y[3]),
                          pack2(y[4],y[5]),  pack2(y[6],y[7]));
    uint4 d1 = make_uint4(pack2(y[8],y[9]),  pack2(y[10],y[11]),
                          pack2(y[12],y[13]),pack2(y[14],y[15]));
    uint4 z = make_uint4(0,0,0,0);
    uint4* rowp = (uint4*)(XB + tid * XS);
    rowp[0 ^ sw] = d0;
    rowp[1 ^ sw] = d1;
    rowp[2 ^ sw] = z;
    rowp[3 ^ sw] = z;
  }

  int wave = tid >> 6, lane = tid & 63;
  int m15 = lane & 15, q = lane >> 4;
  int mtb = wave * 4;

  // ---- layer1: 16(pad32) -> 64 ----
  {
    bf16x8 af[4];
    #pragma unroll
    for (int t4 = 0; t4 < 4; t4++) {
      int row = (mtb + t4) * 16 + m15;
      af[t4] = *(const bf16x8*)(XB + row * XS + ((q ^ (row & 7)) * 8));
    }
    #pragma unroll
    for (int nt = 0; nt < 4; nt++) {
      bf16x8 bf_ = *(const bf16x8*)(VP + VP0OFF + nt * 512 + (q * 16 + m15) * 8);
      float bias = w[WR_C0 + nt * 16 + m15];
      int g = nt * 2 + (m15 >> 3), off = m15 & 7;
      #pragma unroll
      for (int t4 = 0; t4 < 4; t4++) {
        f32x4 acc = (f32x4){0.f,0.f,0.f,0.f};
        acc = __builtin_amdgcn_mfma_f32_16x16x32_bf16(af[t4], bf_, acc, 0, 0, 0);
        int pbase = (mtb + t4) * 16 + q * 4;
        #pragma unroll
        for (int reg = 0; reg < 4; reg++) {
          int row = pbase + reg;
          XB[row * XS + ((g ^ (row & 7)) * 8 + off)] = f2bf(fmaxf(acc[reg] + bias, 0.f));
        }
      }
    }
  }
  // ---- layers 2,3: 64 -> 64, in-place (frag preload) ----
  #pragma unroll
  for (int layer = 0; layer < 2; layer++) {
    int vpo  = layer ? VP2OFF : VP1OFF;
    int wrc  = layer ? WR_C2  : WR_C1;
    bf16x8 af[8];
    #pragma unroll
    for (int t4 = 0; t4 < 4; t4++) {
      int row = (mtb + t4) * 16 + m15;
      #pragma unroll
      for (int kc = 0; kc < 2; kc++)
        af[t4*2+kc] = *(const bf16x8*)(XB + row * XS + (((kc*4 + q) ^ (row & 7)) * 8));
    }
    #pragma unroll
    for (int nt = 0; nt < 4; nt++) {
      bf16x8 b0 = *(const bf16x8*)(VP + vpo + (0 * 4 + nt) * 512 + (q * 16 + m15) * 8);
      bf16x8 b1 = *(const bf16x8*)(VP + vpo + (1 * 4 + nt) * 512 + (q * 16 + m15) * 8);
      float bias = w[wrc + nt * 16 + m15];
      int g = nt * 2 + (m15 >> 3), off = m15 & 7;
      #pragma unroll
      for (int t4 = 0; t4 < 4; t4++) {
        f32x4 acc = (f32x4){0.f,0.f,0.f,0.f};
        acc = __builtin_amdgcn_mfma_f32_16x16x32_bf16(af[t4*2+0], b0, acc, 0, 0, 0);
        acc = __builtin_amdgcn_mfma_f32_16x16x32_bf16(af[t4*2+1], b1, acc, 0, 0, 0);
        int pbase = (mtb + t4) * 16 + q * 4;
        #pragma unroll
        for (int reg = 0; reg < 4; reg++) {
          int row = pbase + reg;
          XB[row * XS + ((g ^ (row & 7)) * 8 + off)] = f2bf(fmaxf(acc[reg] + bias, 0.f));
        }
      }
    }
  }
  // ---- layer4: 64 -> 16 -> regs ----
  f32x4 acc4[4];
  float bias4;
  {
    bf16x8 af[8];
    #pragma unroll
    for (int t4 = 0; t4 < 4; t4++) {
      int row = (mtb + t4) * 16 + m15;
      #pragma unroll
      for (int kc = 0; kc < 2; kc++)
        af[t4*2+kc] = *(const bf16x8*)(XB + row * XS + (((kc*4 + q) ^ (row & 7)) * 8));
    }
    bf16x8 b0 = *(const bf16x8*)(VP + VP3OFF + 0 * 512 + (q * 16 + m15) * 8);
    bf16x8 b1 = *(const bf16x8*)(VP + VP3OFF + 1 * 512 + (q * 16 + m15) * 8);
    bias4 = w[WR_C3 + m15];
    #pragma unroll
    for (int t4 = 0; t4 < 4; t4++) {
      f32x4 acc = (f32x4){0.f,0.f,0.f,0.f};
      acc = __builtin_amdgcn_mfma_f32_16x16x32_bf16(af[t4*2+0], b0, acc, 0, 0, 0);
      acc = __builtin_amdgcn_mfma_f32_16x16x32_bf16(af[t4*2+1], b1, acc, 0, 0, 0);
      acc4[t4] = acc;
    }
  }
  __syncthreads();   // RRB aliases XB across wave rows
  float* RRB = (float*)XB;
  #pragma unroll
  for (int t4 = 0; t4 < 4; t4++) {
    int pbase = (mtb + t4) * 16 + q * 4;
    #pragma unroll
    for (int reg = 0; reg < 4; reg++)
      RRB[(pbase + reg) * RSTR + m15] = acc4[t4][reg] + bias4;
  }
  float rr[16];
  {
    const float4* rp = (const float4*)(RRB + tid * RSTR);
    float4 v0 = rp[0], v1 = rp[1], v2 = rp[2], v3 = rp[3];
    rr[0]=v0.x; rr[1]=v0.y; rr[2]=v0.z; rr[3]=v0.w;
    rr[4]=v1.x; rr[5]=v1.y; rr[6]=v1.z; rr[7]=v1.w;
    rr[8]=v2.x; rr[9]=v2.y; rr[10]=v2.z; rr[11]=v2.w;
    rr[12]=v3.x; rr[13]=v3.y; rr[14]=v3.z; rr[15]=v3.w;
  }
  size_t base = (size_t)i * 8192 + (size_t)k * 16;
  float mv[16];
  load16f(mtr, base, f32, mv);
  if (f32) {
    float4* op = (float4*)((float*)out + base);
    op[0] = make_float4(mv[0]+rr[0],  mv[1]+rr[1],  mv[2]+rr[2],  mv[3]+rr[3]);
    op[1] = make_float4(mv[4]+rr[4],  mv[5]+rr[5],  mv[6]+rr[6],  mv[7]+rr[7]);
    op[2] = make_float4(mv[8]+rr[8],  mv[9]+rr[9],  mv[10]+rr[10],mv[11]+rr[11]);
    op[3] = make_float4(mv[12]+rr[12],mv[13]+rr[13],mv[14]+rr[14],mv[15]+rr[15]);
  } else {
    unsigned pw[8];
    #pragma unroll
    for (int q2 = 0; q2 < 8; q2++)
      pw[q2] = pack2(mv[2*q2] + rr[2*q2], mv[2*q2+1] + rr[2*q2+1]);
    uint4* op = (uint4*)((__hip_bfloat16*)out + base);
    op[0] = make_uint4(pw[0], pw[1], pw[2], pw[3]);
    op[1] = make_uint4(pw[4], pw[5], pw[6], pw[7]);
  }
}

// ================= fallback path (small ws) =================
__global__ void prep_weights(
  const void* __restrict__ W0, const void* __restrict__ b0,
  const void* __restrict__ W1, const void* __restrict__ b1,
  const void* __restrict__ W2, const void* __restrict__ b2,
  const void* __restrict__ W3, const void* __restrict__ b3,
  const void* __restrict__ V0, const void* __restrict__ c0,
  const void* __restrict__ V1, const void* __restrict__ c1,
  const void* __restrict__ V2, const void* __restrict__ c2,
  const void* __restrict__ V3, const void* __restrict__ c3,
  const void* __restrict__ L,  const void* __restrict__ Lb,
  const unsigned short* __restrict__ mtr_u16,
  int* __restrict__ flag, float* __restrict__ w)
{
  __shared__ float mx[256];
  int tid = threadIdx.x;
  float m = 0.f;
  for (int t = tid; t < 4096; t += 256) {
    float v = __uint_as_float(((unsigned)mtr_u16[t]) << 16);
    if (v != v) m = 3e38f;
    else m = fmaxf(m, fabsf(v));
  }
  mx[tid] = m;
  __syncthreads();
  for (int s = 128; s > 0; s >>= 1) {
    if (tid < s) mx[tid] = fmaxf(mx[tid], mx[tid + s]);
    __syncthreads();
  }
  const int f32 = (mx[0] > 1e6f) ? 1 : 0;
  if (blockIdx.x == 0 && tid == 0) flag[0] = f32;

  int g = blockIdx.x * blockDim.x + tid;
  int stride = gridDim.x * blockDim.x;
  auto cv = [&](const void* p, int off, int n){
    for (int i = g; i < n; i += stride) w[off + i] = ldelem(p, i, f32);
  };
  cv(W0, WR_W0, 512);  cv(b0, WR_B0, 64);
  cv(W1, WR_W1, 4096); cv(b1, WR_B1, 64);
  cv(W2, WR_W2, 4096); cv(b2, WR_B2, 64);
  cv(W3, WR_W3, 16384);cv(b3, WR_B3, 256);
  for (int idx = g; idx < 1024; idx += stride) {
    int j = idx >> 4, t = idx & 15;
    w[WR_V0T + idx] = ldelem(V0, t * 64 + j, f32);
  }
  cv(c0, WR_C0, 64);
  cv(V1, WR_V1, 4096); cv(c1, WR_C1, 64);
  cv(V2, WR_V2, 4096); cv(c2, WR_C2, 64);
  cv(V3, WR_V3, 1024); cv(c3, WR_C3, 16);
  cv(L,  WR_L,  256);  cv(Lb, WR_LB, 16);
}

__global__ void build_bins_basic(const int* __restrict__ ei,
                                 int* __restrict__ offs, int* __restrict__ sorted)
{
  __shared__ int cnt[512];
  __shared__ int cur[512];
  int tid = threadIdx.x;
  cnt[tid] = 0;
  __syncthreads();
  for (int e = tid; e < EE; e += 512) atomicAdd(&cnt[ei[EE + e]], 1);
  __syncthreads();
  int myc = cnt[tid];
  for (int off = 1; off < 512; off <<= 1) {
    int add = (tid >= off) ? cnt[tid - off] : 0;
    __syncthreads();
    cnt[tid] += add;
    __syncthreads();
  }
  int excl = cnt[tid] - myc;
  offs[tid] = excl;
  if (tid == 511) offs[512] = cnt[511];
  cur[tid] = excl;
  __syncthreads();
  for (int e = tid; e < EE; e += 512) {
    int d = ei[EE + e];
    sorted[atomicAdd(&cur[d], 1)] = e;
  }
}

__global__ __launch_bounds__(256) void edge_mlp_fb(
  const void* __restrict__ ea, const float* __restrict__ w,
  const int* __restrict__ flag, float* __restrict__ Fws)
{
  const int f32 = flag[0];
  const float* W0f = w + WR_W0; const float* b0f = w + WR_B0;
  const float* W1f = w + WR_W1; const float* b1f = w + WR_B1;
  const float* W2f = w + WR_W2; const float* b2f = w + WR_B2;
  const float* W3f = w + WR_W3; const float* b3f = w + WR_B3;
  int tid = threadIdx.x;
  int eg = tid >> 6, lane = tid & 63;
  int e = blockIdx.x * 4 + eg;
  __shared__ float shA[4][64];
  __shared__ float shB[4][64];
  float x[8];
  #pragma unroll
  for (int c = 0; c < 8; c++) x[c] = ldelem(ea, e * 8 + c, f32);
  float s = b0f[lane];
  #pragma unroll
  for (int c = 0; c < 8; c++) s += x[c] * W0f[c * 64 + lane];
  shA[eg][lane] = fmaxf(s, 0.f);
  __syncthreads();
  s = b1f[lane];
  #pragma unroll
  for (int c = 0; c < 64; c++) s += shA[eg][c] * W1f[c * 64 + lane];
  shB[eg][lane] = fmaxf(s, 0.f);
  __syncthreads();
  s = b2f[lane];
  #pragma unroll
  for (int c = 0; c < 64; c++) s += shB[eg][c] * W2f[c * 64 + lane];
  shA[eg][lane] = fmaxf(s, 0.f);
  __syncthreads();
  #pragma unroll
  for (int r2 = 0; r2 < 4; r2++) {
    int o = r2 * 64 + lane;
    float t = b3f[o];
    #pragma unroll
    for (int c = 0; c < 64; c++) t += shA[eg][c] * W3f[c * 256 + o];
    Fws[(size_t)e * 256 + o] = t;
  }
}

__global__ __launch_bounds__(256) void message_kernel_direct(
  const void* __restrict__ mtr, const int* __restrict__ ei,
  const float* __restrict__ Fws, const int* __restrict__ offs,
  const int* __restrict__ sorted, const int* __restrict__ flag,
  float* __restrict__ mtr1T)
{
  const int f32 = flag[0];
  int k = blockIdx.x;
  int i = blockIdx.y * 256 + threadIdx.x;
  float acc[16];
  #pragma unroll
  for (int t = 0; t < 16; t++) acc[t] = 0.f;
  int j0 = offs[k], j1 = offs[k + 1];
  for (int j = j0; j < j1; j++) {
    int e = __builtin_amdgcn_readfirstlane(sorted[j]);
    int s = __builtin_amdgcn_readfirstlane(ei[e]);
    float m[16];
    load16f(mtr, (size_t)i * 8192 + s * 16, f32, m);
    const float4* Fe = (const float4*)(Fws + (size_t)e * 256);
    #pragma unroll
    for (int c = 0; c < 16; c++) {
      float4 f0 = Fe[c*4+0], f1 = Fe[c*4+1], f2 = Fe[c*4+2], f3 = Fe[c*4+3];
      acc[0]  += m[c]*f0.x; acc[1]  += m[c]*f0.y; acc[2]  += m[c]*f0.z; acc[3]  += m[c]*f0.w;
      acc[4]  += m[c]*f1.x; acc[5]  += m[c]*f1.y; acc[6]  += m[c]*f1.z; acc[7]  += m[c]*f1.w;
      acc[8]  += m[c]*f2.x; acc[9]  += m[c]*f2.y; acc[10] += m[c]*f2.z; acc[11] += m[c]*f2.w;
      acc[12] += m[c]*f3.x; acc[13] += m[c]*f3.y; acc[14] += m[c]*f3.z; acc[15] += m[c]*f3.w;
    }
  }
  float4* op = (float4*)(mtr1T + (size_t)k * 8192 + i * 16);
  op[0] = make_float4(acc[0],  acc[1],  acc[2],  acc[3]);
  op[1] = make_float4(acc[4],  acc[5],  acc[6],  acc[7]);
  op[2] = make_float4(acc[8],  acc[9],  acc[10], acc[11]);
  op[3] = make_float4(acc[12], acc[13], acc[14], acc[15]);
}

__global__ __launch_bounds__(256, 4) void final_kernel_fb(
  const void* __restrict__ mtr, const float* __restrict__ w,
  const float* __restrict__ mtr1T, const int* __restrict__ flag,
  void* __restrict__ out)
{
  const int f32 = flag[0];
  __shared__ unsigned hbuf[32 * 256];
  int tid = threadIdx.x;
  int ti = blockIdx.x >> 5, tk = blockIdx.x & 31;
  int r = tid >> 4, c = tid & 15;
  int i = ti * 16 + r, k = tk * 16 + c;
  float scale = (i == k) ? 0.f : 0.0625f;
  float y[16];
  {
    float a[16], b[16];
    const float4* pa = (const float4*)(mtr1T + (size_t)k * 8192 + (size_t)i * 16);
    const float4* pb = (const float4*)(mtr1T + (size_t)i * 8192 + (size_t)k * 16);
    #pragma unroll
    for (int q = 0; q < 4; q++) {
      float4 va = pa[q], vb = pb[q];
      a[q*4+0]=va.x*scale; a[q*4+1]=va.y*scale; a[q*4+2]=va.z*scale; a[q*4+3]=va.w*scale;
      b[q*4+0]=vb.x*scale; b[q*4+1]=vb.y*scale; b[q*4+2]=vb.z*scale; b[q*4+3]=vb.w*scale;
    }
    const float* Lf  = w + WR_L;
    const float* Lbf = w + WR_LB;
    #pragma unroll
    for (int t = 0; t < 16; t++) y[t] = a[t] + Lbf[t];
    #pragma unroll
    for (int cc = 0; cc < 16; cc++) {
      #pragma unroll
      for (int t = 0; t < 16; t++) y[t] += b[cc] * Lf[cc * 16 + t];
    }
  }
  {
    const float* V0t = w + WR_V0T; const float* c0f = w + WR_C0;
    for (int m = 0; m < 32; m++) {
      float s0 = c0f[2*m], s1 = c0f[2*m+1];
      #pragma unroll
      for (int t = 0; t < 16; t++) {
        s0 += y[t] * V0t[(2*m) * 16 + t];
        s1 += y[t] * V0t[(2*m+1) * 16 + t];
      }
      hbuf[m * 256 + tid] = pack2(fmaxf(s0, 0.f), fmaxf(s1, 0.f));
    }
  }
  #pragma unroll
  for (int lyr = 0; lyr < 2; lyr++) {
    const float* Vf = w + (lyr ? WR_V2 : WR_V1);
    const float* cf = w + (lyr ? WR_C2 : WR_C1);
    unsigned held[16];
    #pragma unroll
    for (int pass = 0; pass < 2; pass++) {
      float s[32];
      #pragma unroll
      for (int jj = 0; jj < 32; jj++) s[jj] = cf[pass * 32 + jj];
      for (int m = 0; m < 32; m++) {
        unsigned hu = hbuf[m * 256 + tid];
        float h0 = bflo(hu), h1 = bfhi(hu);
        #pragma unroll
        for (int jj = 0; jj < 32; jj++)
          s[jj] += h0 * Vf[(2*m) * 64 + pass*32 + jj] + h1 * Vf[(2*m+1) * 64 + pass*32 + jj];
      }
      if (pass == 0) {
        #pragma unroll
        for (int q = 0; q < 16; q++) held[q] = pack2(fmaxf(s[2*q], 0.f), fmaxf(s[2*q+1], 0.f));
      } else {
        #pragma unroll
        for (int q = 0; q < 16; q++) hbuf[q * 256 + tid] = held[q];
        #pragma unroll
        for (int q = 0; q < 16; q++) hbuf[(16 + q) * 256 + tid] = pack2(fmaxf(s[2*q], 0.f), fmaxf(s[2*q+1], 0.f));
      }
    }
  }
  float rr[16];
  {
    const float* V3f = w + WR_V3; const float* c3f = w + WR_C3;
    #pragma unroll
    for (int t = 0; t < 16; t++) rr[t] = c3f[t];
    for (int m = 0; m < 32; m++) {
      unsigned hu = hbuf[m * 256 + tid];
      float h0 = bflo(hu), h1 = bfhi(hu);
      #pragma unroll
      for (int t = 0; t < 16; t++)
        rr[t] += h0 * V3f[(2*m) * 16 + t] + h1 * V3f[(2*m+1) * 16 + t];
    }
  }
  size_t base = (size_t)i * 8192 + (size_t)k * 16;
  float mv[16];
  load16f(mtr, base, f32, mv);
  if (f32) {
    float4* op = (float4*)((float*)out + base);
    op[0] = make_float4(mv[0]+rr[0],  mv[1]+rr[1],  mv[2]+rr[2],  mv[3]+rr[3]);
    op[1] = make_float4(mv[4]+rr[4],  mv[5]+rr[5],  mv[6]+rr[6],  mv[7]+rr[7]);
    op[2] = make_float4(mv[8]+rr[8],  mv[9]+rr[9],  mv[10]+rr[10],mv[11]+rr[11]);
    op[3] = make_float4(mv[12]+rr[12],mv[13]+rr[13],mv[14]+rr[14],mv[15]+rr[15]);
  } else {
    unsigned pw[8];
    #pragma unroll
    for (int q = 0; q < 8; q++)
      pw[q] = pack2(mv[2*q] + rr[2*q], mv[2*q+1] + rr[2*q+1]);
    uint4* op = (uint4*)((__hip_bfloat16*)out + base);
    op[0] = make_uint4(pw[0], pw[1], pw[2], pw[3]);
    op[1] = make_uint4(pw[4], pw[5], pw[6], pw[7]);
  }
}

extern "C" void kernel_launch(void* const* d_in, const int* in_sizes, int n_in,
                              void* d_out, int out_size, void* d_ws, size_t ws_size,
                              hipStream_t stream)
{
  const void* mtr = d_in[0];
  const void* ea  = d_in[1];
  const int*  ei  = (const int*)d_in[2];

  float* ws    = (float*)d_ws;
  float* Fws   = ws + OFF_F;
  float* mtr1T = ws + OFF_MTR1;
  __hip_bfloat16* mtr1B = (__hip_bfloat16*)(ws + OFF_MTR1);
  float* w     = ws + OFF_W;
  int* offs    = (int*)(ws + OFF_OFFS);
  int* sorted  = (int*)(ws + OFF_SORTED);
  int* flag    = (int*)(ws + OFF_FLAG);
  __hip_bfloat16* mtrT = (__hip_bfloat16*)(ws + OFF_MTRT);
  int* offsP   = (int*)(ws + OFF_OFFSP);
  unsigned* packP = (unsigned*)(ws + OFF_PACKP);
  unsigned short* Fpack = (unsigned short*)(ws + OFF_FPACK);
  unsigned short* VP    = (unsigned short*)(ws + OFF_VPACK);

  if (ws_size >= WS_FULL2_BYTES) {
    prep_all<<<1573, 512, 0, stream>>>(
        mtr, ea, ei,
        d_in[3], d_in[4], d_in[5], d_in[6], d_in[7], d_in[8], d_in[9], d_in[10],
        d_in[11], d_in[12], d_in[13], d_in[14], d_in[15], d_in[16], d_in[17], d_in[18],
        d_in[19], d_in[20],
        flag, w, VP, offsP, packP, Fpack, mtrT);
    dim3 gmsg(512, 4);
    message_mfma2<<<gmsg, 256, 0, stream>>>(mtrT, Fpack, offsP, packP, mtr1B);
    final_mfma<<<1024, 256, 0, stream>>>(mtr, w, mtr1B, flag, VP, d_out);
  } else {
    prep_weights<<<32, 256, 0, stream>>>(d_in[3], d_in[4], d_in[5], d_in[6],
                                         d_in[7], d_in[8], d_in[9], d_in[10],
                                         d_in[11], d_in[12], d_in[13], d_in[14],
                                         d_in[15], d_in[16], d_in[17], d_in[18],
                                         d_in[19], d_in[20],
                                         (const unsigned short*)mtr, flag, w);
    build_bins_basic<<<1, 512, 0, stream>>>(ei, offs, sorted);
    edge_mlp_fb<<<EE / 4, 256, 0, stream>>>(ea, w, flag, Fws);
    dim3 gmsg(512, 2);
    message_kernel_direct<<<gmsg, 256, 0, stream>>>(mtr, ei, Fws, offs, sorted, flag, mtr1T);
    final_kernel_fb<<<1024, 256, 0, stream>>>(mtr, w, mtr1T, flag, d_out);
  }
}

// Round 8
// 199.185 us; speedup vs baseline: 1.0755x; 1.0755x over previous
//
#include <hip/hip_runtime.h>
#include <hip/hip_bf16.h>

#define NN 512
#define EE 8192

// ---- workspace layout (float offsets) ----
#define OFF_F     0u
#define OFF_MTR1  2097152u      // full path: N*N*16 bf16 (mtr1B) ; fallback: fp32 mtr1T
#define OFF_W     6291456u
#define WR_W0   0
#define WR_B0   512
#define WR_W1   576
#define WR_B1   4672
#define WR_W2   4736
#define WR_B2   8832
#define WR_W3   8896
#define WR_B3   25280
#define WR_V0T  25536
#define WR_C0   26560
#define WR_V1   26624
#define WR_C1   30720
#define WR_V2   30784
#define WR_C2   34880
#define WR_V3   34944
#define WR_C3   35968
#define WR_L    35984
#define WR_LB   36240
#define W_TOTAL 36256
#define OFF_OFFS    (OFF_W + W_TOTAL)
#define OFF_SORTED  (OFF_OFFS + 513)
#define OFF_FLAG    (OFF_SORTED + EE)
#define OFF_MTRT    6336420u
#define OFF_OFFSP   8433572u
#define OFF_PACKP   8434085u
#define OFF_FPACK   8442792u
#define OFF_VPACK   9491496u
#define WS_NEED_BYTES  ((size_t)(OFF_MTRT  + 2097152u) * 4u)
#define WS_FULL2_BYTES ((size_t)(OFF_VPACK + 5632u) * 4u)

#define VP0OFF 0
#define VP1OFF 2048
#define VP2OFF 6144
#define VP3OFF 10240

#define XS   64   // XB row stride (bf16 units) = 128 B; 256 rows = 32768 B
#define RSTR 20   // RRB row stride, f32

typedef __attribute__((ext_vector_type(8))) short bf16x8;
typedef __attribute__((ext_vector_type(4))) float f32x4;

__device__ __forceinline__ float bflo(unsigned u){ return __uint_as_float(u << 16); }
__device__ __forceinline__ float bfhi(unsigned u){ return __uint_as_float(u & 0xffff0000u); }
__device__ __forceinline__ unsigned short f2bf(float f){
  __hip_bfloat16 h = __float2bfloat16(f);
  union { __hip_bfloat16 hh; unsigned short ss; } u;
  u.hh = h; return u.ss;
}
__device__ __forceinline__ unsigned pack2(float a, float b){
  return (unsigned)f2bf(a) | ((unsigned)f2bf(b) << 16);
}
__device__ __forceinline__ float cvt(float v){ return v; }
__device__ __forceinline__ float cvt(__hip_bfloat16 v){ return __bfloat162float(v); }

__device__ __forceinline__ void load16f(const void* base, size_t eoff, int f32, float m[16]) {
  if (f32) {
    const float4* p = (const float4*)((const float*)base + eoff);
    float4 a = p[0], b = p[1], c = p[2], d = p[3];
    m[0]=a.x; m[1]=a.y; m[2]=a.z; m[3]=a.w;
    m[4]=b.x; m[5]=b.y; m[6]=b.z; m[7]=b.w;
    m[8]=c.x; m[9]=c.y; m[10]=c.z; m[11]=c.w;
    m[12]=d.x; m[13]=d.y; m[14]=d.z; m[15]=d.w;
  } else {
    const uint4* p = (const uint4*)((const __hip_bfloat16*)base + eoff);
    uint4 u0 = p[0], u1 = p[1];
    m[0]=bflo(u0.x);  m[1]=bfhi(u0.x);  m[2]=bflo(u0.y);  m[3]=bfhi(u0.y);
    m[4]=bflo(u0.z);  m[5]=bfhi(u0.z);  m[6]=bflo(u0.w);  m[7]=bfhi(u0.w);
    m[8]=bflo(u1.x);  m[9]=bfhi(u1.x);  m[10]=bflo(u1.y); m[11]=bfhi(u1.y);
    m[12]=bflo(u1.z); m[13]=bfhi(u1.z); m[14]=bflo(u1.w); m[15]=bfhi(u1.w);
  }
}

__device__ __forceinline__ float ldelem(const void* p, int idx, int f32) {
  return f32 ? ((const float*)p)[idx]
             : __bfloat162float(((const __hip_bfloat16*)p)[idx]);
}

__device__ __forceinline__ int detect_f32_local(const unsigned short* mtr_u16, float* red) {
  int tid = threadIdx.x;
  float m = 0.f;
  for (int t = tid; t < 4096; t += 512) {
    float v = __uint_as_float(((unsigned)mtr_u16[t]) << 16);
    if (v != v) m = 3e38f;
    else m = fmaxf(m, fabsf(v));
  }
  red[tid] = m;
  __syncthreads();
  for (int s = 256; s > 0; s >>= 1) {
    if (tid < s) red[tid] = fmaxf(red[tid], red[tid + s]);
    __syncthreads();
  }
  float mx = red[0];
  __syncthreads();
  return (mx > 1e6f) ? 1 : 0;
}

template <typename T>
__device__ void edge_body(const T* __restrict__ ea,
                          const T* __restrict__ W0, const T* __restrict__ b0,
                          const T* __restrict__ W1, const T* __restrict__ b1,
                          const T* __restrict__ W2, const T* __restrict__ b2,
                          const T* __restrict__ W3, const T* __restrict__ b3,
                          int e, int eg, int lane,
                          float (*shA)[64], float (*shB)[64],
                          unsigned short* __restrict__ Fpack)
{
  float x[8];
  #pragma unroll
  for (int c = 0; c < 8; c++) x[c] = cvt(ea[(size_t)e * 8 + c]);

  float s = cvt(b0[lane]);
  #pragma unroll
  for (int c = 0; c < 8; c++) s += x[c] * cvt(W0[c * 64 + lane]);
  shA[eg][lane] = fmaxf(s, 0.f);
  __syncthreads();

  s = cvt(b1[lane]);
  #pragma unroll
  for (int c = 0; c < 64; c++) s += shA[eg][c] * cvt(W1[c * 64 + lane]);
  shB[eg][lane] = fmaxf(s, 0.f);
  __syncthreads();

  s = cvt(b2[lane]);
  #pragma unroll
  for (int c = 0; c < 64; c++) s += shB[eg][c] * cvt(W2[c * 64 + lane]);
  shA[eg][lane] = fmaxf(s, 0.f);
  __syncthreads();

  int quad = lane >> 4, tt = lane & 15;
  #pragma unroll
  for (int r = 0; r < 4; r++) {
    int o = r * 64 + lane;
    float t = cvt(b3[o]);
    #pragma unroll
    for (int c = 0; c < 64; c++) t += shA[eg][c] * cvt(W3[c * 256 + o]);
    int cc = r * 4 + quad;
    Fpack[(size_t)e * 256 + (cc >> 3) * 128 + tt * 8 + (cc & 7)] = f2bf(t);
  }
}

// ---- K1: fused prep (roles by blockIdx.x) ----
__global__ __launch_bounds__(512) void prep_all(
  const void* __restrict__ mtr, const void* __restrict__ ea, const int* __restrict__ ei,
  const void* __restrict__ W0, const void* __restrict__ b0,
  const void* __restrict__ W1, const void* __restrict__ b1,
  const void* __restrict__ W2, const void* __restrict__ b2,
  const void* __restrict__ W3, const void* __restrict__ b3,
  const void* __restrict__ V0, const void* __restrict__ c0,
  const void* __restrict__ V1, const void* __restrict__ c1,
  const void* __restrict__ V2, const void* __restrict__ c2,
  const void* __restrict__ V3, const void* __restrict__ c3,
  const void* __restrict__ L,  const void* __restrict__ Lb,
  int* __restrict__ flag, float* __restrict__ w, unsigned short* __restrict__ VP,
  int* __restrict__ offsP, unsigned* __restrict__ packP,
  unsigned short* __restrict__ Fpack, __hip_bfloat16* __restrict__ mtrT)
{
  __shared__ __attribute__((aligned(16))) char smem_raw[8192];
  int tid = threadIdx.x;
  int bid = blockIdx.x;
  const int f32 = detect_f32_local((const unsigned short*)mtr, (float*)smem_raw);

  if (bid == 0) {
    int* cnt  = (int*)smem_raw;
    int* pcs  = cnt + 512;
    int* curP = pcs + 512;
    cnt[tid] = 0;
    if (tid == 0) flag[0] = f32;
    __syncthreads();
    for (int e = tid; e < EE; e += 512) atomicAdd(&cnt[ei[EE + e]], 1);
    __syncthreads();
    int myc = cnt[tid];
    int myp = (myc + 1) & ~1;
    pcs[tid] = myp;
    __syncthreads();
    for (int off = 1; off < 512; off <<= 1) {
      int b = (tid >= off) ? pcs[tid - off] : 0;
      __syncthreads();
      pcs[tid] += b;
      __syncthreads();
    }
    int excP = pcs[tid] - myp;
    offsP[tid] = excP;
    if (tid == 511) offsP[512] = pcs[511];
    curP[tid] = excP;
    if (myc & 1) packP[excP + myc] = EE;
    __syncthreads();
    for (int e = tid; e < EE; e += 512) {
      int d = ei[EE + e];
      int s = ei[e];
      packP[atomicAdd(&curP[d], 1)] = (unsigned)e | ((unsigned)s << 14);
    }
    unsigned* fz = (unsigned*)(Fpack + (size_t)EE * 256);
    for (int i2 = tid; i2 < 128; i2 += 512) fz[i2] = 0u;
  } else if (bid < 33) {
    int g = (bid - 1) * 512 + tid;
    const int stride = 32 * 512;
    auto cv = [&](const void* p, int off, int n){
      for (int i = g; i < n; i += stride) w[off + i] = ldelem(p, i, f32);
    };
    cv(W0, WR_W0, 512);  cv(b0, WR_B0, 64);
    cv(W1, WR_W1, 4096); cv(b1, WR_B1, 64);
    cv(W2, WR_W2, 4096); cv(b2, WR_B2, 64);
    cv(W3, WR_W3, 16384);cv(b3, WR_B3, 256);
    for (int idx = g; idx < 1024; idx += stride) {
      int j = idx >> 4, t = idx & 15;
      w[WR_V0T + idx] = ldelem(V0, t * 64 + j, f32);
    }
    cv(c0, WR_C0, 64);
    cv(V1, WR_V1, 4096); cv(c1, WR_C1, 64);
    cv(V2, WR_V2, 4096); cv(c2, WR_C2, 64);
    cv(V3, WR_V3, 1024); cv(c3, WR_C3, 16);
    cv(L,  WR_L,  256);  cv(Lb, WR_LB, 16);
  } else if (bid < 37) {
    int g = (bid - 33) * 512 + tid;
    const int stride = 4 * 512;
    for (int idx = g; idx < 2048; idx += stride) {
      int j = idx & 7, lp = (idx >> 3) & 63, nt = idx >> 9;
      int nn = lp & 15, qq = lp >> 4;
      int kk = qq * 8 + j;
      float v = (kk < 16) ? ldelem(V0, kk * 64 + nt * 16 + nn, f32) : 0.f;
      VP[VP0OFF + idx] = f2bf(v);
    }
    for (int idx = g; idx < 4096; idx += stride) {
      int j = idx & 7, lp = (idx >> 3) & 63, tile = idx >> 9;
      int nn = lp & 15, qq = lp >> 4;
      int kc = tile >> 2, nt = tile & 3;
      int kk = kc * 32 + qq * 8 + j;
      VP[VP1OFF + idx] = f2bf(ldelem(V1, kk * 64 + nt * 16 + nn, f32));
      VP[VP2OFF + idx] = f2bf(ldelem(V2, kk * 64 + nt * 16 + nn, f32));
    }
    for (int idx = g; idx < 1024; idx += stride) {
      int j = idx & 7, lp = (idx >> 3) & 63, kc = idx >> 9;
      int nn = lp & 15, qq = lp >> 4;
      int kk = kc * 32 + qq * 8 + j;
      VP[VP3OFF + idx] = f2bf(ldelem(V3, kk * 16 + nn, f32));
    }
  } else if (bid < 549) {
    int s = bid - 37;
    int i = tid;
    float m[16];
    load16f(mtr, (size_t)i * 8192 + (size_t)s * 16, f32, m);
    unsigned pw[8];
    #pragma unroll
    for (int q = 0; q < 8; q++) pw[q] = pack2(m[2*q], m[2*q+1]);
    uint4* op = (uint4*)(mtrT + (size_t)s * 8192 + (size_t)i * 16);
    op[0] = make_uint4(pw[0], pw[1], pw[2], pw[3]);
    op[1] = make_uint4(pw[4], pw[5], pw[6], pw[7]);
  } else {
    int eg = tid >> 6, lane = tid & 63;
    int e = (bid - 549) * 8 + eg;
    float (*shA)[64] = (float(*)[64])smem_raw;
    float (*shB)[64] = (float(*)[64])(smem_raw + 2048);
    if (f32)
      edge_body<float>((const float*)ea,
        (const float*)W0, (const float*)b0, (const float*)W1, (const float*)b1,
        (const float*)W2, (const float*)b2, (const float*)W3, (const float*)b3,
        e, eg, lane, shA, shB, Fpack);
    else
      edge_body<__hip_bfloat16>((const __hip_bfloat16*)ea,
        (const __hip_bfloat16*)W0, (const __hip_bfloat16*)b0,
        (const __hip_bfloat16*)W1, (const __hip_bfloat16*)b1,
        (const __hip_bfloat16*)W2, (const __hip_bfloat16*)b2,
        (const __hip_bfloat16*)W3, (const __hip_bfloat16*)b3,
        e, eg, lane, shA, shB, Fpack);
  }
}

// ---- K2: message via MFMA; grid (512 k, 4 i-quarters); bf16 mtr1 output ----
__global__ __launch_bounds__(256) void message_mfma2(
  const __hip_bfloat16* __restrict__ mtrT,
  const unsigned short* __restrict__ Fpack,
  const int* __restrict__ offsP, const unsigned* __restrict__ packP,
  __hip_bfloat16* __restrict__ mtr1B)
{
  int k = blockIdx.x;
  int tid = threadIdx.x;
  int wave = tid >> 6, lane = tid & 63;
  int n = lane & 15, quad = lane >> 4;
  int qh = quad >> 1, qq = quad & 1;
  int ibase = blockIdx.y * 128 + wave * 32;
  int j0 = offsP[k], j1 = offsP[k + 1];

  f32x4 acc0 = (f32x4){0.f,0.f,0.f,0.f};
  f32x4 acc1 = (f32x4){0.f,0.f,0.f,0.f};

  bf16x8 bfrag, af0, af1;
  auto loadfr = [&](int j) {
    unsigned p1 = __builtin_amdgcn_readfirstlane(packP[j]);
    unsigned p2 = __builtin_amdgcn_readfirstlane(packP[j + 1]);
    unsigned pv = qh ? p2 : p1;
    int es = (int)(pv & 0x3FFFu);
    int ss = (int)(pv >> 14);
    bfrag = *(const bf16x8*)(Fpack + (size_t)es * 256 + (qq * 16 + n) * 8);
    const __hip_bfloat16* ab = mtrT + (size_t)ss * 8192 + qq * 8;
    af0 = *(const bf16x8*)(ab + (size_t)(ibase + 0 * 16 + n) * 16);
    af1 = *(const bf16x8*)(ab + (size_t)(ibase + 1 * 16 + n) * 16);
  };
  if (j0 < j1) loadfr(j0);
  for (int j = j0; j < j1; j += 2) {
    bf16x8 bc = bfrag, a0 = af0, a1 = af1;
    if (j + 2 < j1) loadfr(j + 2);
    acc0 = __builtin_amdgcn_mfma_f32_16x16x32_bf16(a0, bc, acc0, 0, 0, 0);
    acc1 = __builtin_amdgcn_mfma_f32_16x16x32_bf16(a1, bc, acc1, 0, 0, 0);
  }

  __hip_bfloat16* obase = mtr1B + (size_t)k * 8192;
  #pragma unroll
  for (int reg = 0; reg < 4; reg++) {
    int r0 = ibase + 0 * 16 + quad * 4 + reg;
    int r1 = ibase + 1 * 16 + quad * 4 + reg;
    obase[(size_t)r0 * 16 + n] = __float2bfloat16(acc0[reg]);
    obase[(size_t)r1 * 16 + n] = __float2bfloat16(acc1[reg]);
  }
}

// ---- K3: final via MFMA; coalesced LDS tile staging + swizzled 32 KB XB ----
// __launch_bounds__(256,4): (256,5) spilled to scratch (R7: WRITE 16->84 MB) — keep 4.
__global__ __launch_bounds__(256, 4) void final_mfma(
  const void* __restrict__ mtr, const float* __restrict__ w,
  const __hip_bfloat16* __restrict__ mtr1B, const int* __restrict__ flag,
  const unsigned short* __restrict__ VP, void* __restrict__ out)
{
  const int f32 = flag[0];
  __shared__ __attribute__((aligned(16))) unsigned short XB[256 * XS];  // 32768 B
  int tid = threadIdx.x;
  int ti = blockIdx.x >> 5, tk = blockIdx.x & 31;
  int i0 = ti * 16, k0 = tk * 16;

  // ---- stage A (rows k0.., cols i0..) and B (rows i0.., cols k0..), coalesced ----
  {
    int row = tid >> 4, off = tid & 15;
    const uint4* ga = (const uint4*)(mtr1B + (size_t)(k0 + row) * 8192 + (size_t)i0 * 16);
    const uint4* gb = (const uint4*)(mtr1B + (size_t)(i0 + row) * 8192 + (size_t)k0 * 16);
    uint4* la = (uint4*)(XB + row * 264);
    uint4* lb = (uint4*)(XB + 4224 + row * 264);
    la[off*2]   = ga[off*2];
    la[off*2+1] = ga[off*2+1];
    lb[off*2]   = gb[off*2];
    lb[off*2+1] = gb[off*2+1];
  }
  __syncthreads();

  int r = tid >> 4, c = tid & 15;
  int i = i0 + r, k = k0 + c;
  float scale = (i == k) ? 0.f : 0.0625f;

  float y[16];
  {
    const uint4* ap = (const uint4*)(XB + c * 264 + r * 16);
    const uint4* bp = (const uint4*)(XB + 4224 + r * 264 + c * 16);
    uint4 a0 = ap[0], a1 = ap[1], b0 = bp[0], b1 = bp[1];
    float a_[16], b_[16];
    a_[0]=bflo(a0.x);  a_[1]=bfhi(a0.x);  a_[2]=bflo(a0.y);  a_[3]=bfhi(a0.y);
    a_[4]=bflo(a0.z);  a_[5]=bfhi(a0.z);  a_[6]=bflo(a0.w);  a_[7]=bfhi(a0.w);
    a_[8]=bflo(a1.x);  a_[9]=bfhi(a1.x);  a_[10]=bflo(a1.y); a_[11]=bfhi(a1.y);
    a_[12]=bflo(a1.z); a_[13]=bfhi(a1.z); a_[14]=bflo(a1.w); a_[15]=bfhi(a1.w);
    b_[0]=bflo(b0.x);  b_[1]=bfhi(b0.x);  b_[2]=bflo(b0.y);  b_[3]=bfhi(b0.y);
    b_[4]=bflo(b0.z);  b_[5]=bfhi(b0.z);  b_[6]=bflo(b0.w);  b_[7]=bfhi(b0.w);
    b_[8]=bflo(b1.x);  b_[9]=bfhi(b1.x);  b_[10]=bflo(b1.y); b_[11]=bfhi(b1.y);
    b_[12]=bflo(b1.z); b_[13]=bfhi(b1.z); b_[14]=bflo(b1.w); b_[15]=bfhi(b1.w);
    const float* Lf  = w + WR_L;
    const float* Lbf = w + WR_LB;
    #pragma unroll
    for (int t = 0; t < 16; t++) y[t] = a_[t] * scale + Lbf[t];
    #pragma unroll
    for (int cc = 0; cc < 16; cc++) {
      float bs = b_[cc] * scale;
      #pragma unroll
      for (int t = 0; t < 16; t++) y[t] += bs * Lf[cc * 16 + t];
    }
  }
  __syncthreads();   // tiles dead; region becomes swizzled XB

  // ---- stage y: row=tid, logical 16B-groups g, phys gp = g ^ (row&7) ----
  {
    unsigned sw = tid & 7;
    uint4 d0 = make_uint4(pack2(y[0],y[1]),  pack2(y[2],y[3]),
                          pack2(y[4],y[5]),  pack2(y[6],y[7]));
    uint4 d1 = make_uint4(pack2(y[8],y[9]),  pack2(y[10],y[11]),
                          pack2(y[12],y[13]),pack2(y[14],y[15]));
    uint4 z = make_uint4(0,0,0,0);
    uint4* rowp = (uint4*)(XB + tid * XS);
    rowp[0 ^ sw] = d0;
    rowp[1 ^ sw] = d1;
    rowp[2 ^ sw] = z;
    rowp[3 ^ sw] = z;
  }

  int wave = tid >> 6, lane = tid & 63;
  int m15 = lane & 15, q = lane >> 4;
  int mtb = wave * 4;

  // ---- layer1: 16(pad32) -> 64 ----
  {
    bf16x8 af[4];
    #pragma unroll
    for (int t4 = 0; t4 < 4; t4++) {
      int row = (mtb + t4) * 16 + m15;
      af[t4] = *(const bf16x8*)(XB + row * XS + ((q ^ (row & 7)) * 8));
    }
    #pragma unroll
    for (int nt = 0; nt < 4; nt++) {
      bf16x8 bf_ = *(const bf16x8*)(VP + VP0OFF + nt * 512 + (q * 16 + m15) * 8);
      float bias = w[WR_C0 + nt * 16 + m15];
      int g = nt * 2 + (m15 >> 3), off = m15 & 7;
      #pragma unroll
      for (int t4 = 0; t4 < 4; t4++) {
        f32x4 acc = (f32x4){0.f,0.f,0.f,0.f};
        acc = __builtin_amdgcn_mfma_f32_16x16x32_bf16(af[t4], bf_, acc, 0, 0, 0);
        int pbase = (mtb + t4) * 16 + q * 4;
        #pragma unroll
        for (int reg = 0; reg < 4; reg++) {
          int row = pbase + reg;
          XB[row * XS + ((g ^ (row & 7)) * 8 + off)] = f2bf(fmaxf(acc[reg] + bias, 0.f));
        }
      }
    }
  }
  // ---- layers 2,3: 64 -> 64, in-place (frag preload) ----
  #pragma unroll
  for (int layer = 0; layer < 2; layer++) {
    int vpo  = layer ? VP2OFF : VP1OFF;
    int wrc  = layer ? WR_C2  : WR_C1;
    bf16x8 af[8];
    #pragma unroll
    for (int t4 = 0; t4 < 4; t4++) {
      int row = (mtb + t4) * 16 + m15;
      #pragma unroll
      for (int kc = 0; kc < 2; kc++)
        af[t4*2+kc] = *(const bf16x8*)(XB + row * XS + (((kc*4 + q) ^ (row & 7)) * 8));
    }
    #pragma unroll
    for (int nt = 0; nt < 4; nt++) {
      bf16x8 b0 = *(const bf16x8*)(VP + vpo + (0 * 4 + nt) * 512 + (q * 16 + m15) * 8);
      bf16x8 b1 = *(const bf16x8*)(VP + vpo + (1 * 4 + nt) * 512 + (q * 16 + m15) * 8);
      float bias = w[wrc + nt * 16 + m15];
      int g = nt * 2 + (m15 >> 3), off = m15 & 7;
      #pragma unroll
      for (int t4 = 0; t4 < 4; t4++) {
        f32x4 acc = (f32x4){0.f,0.f,0.f,0.f};
        acc = __builtin_amdgcn_mfma_f32_16x16x32_bf16(af[t4*2+0], b0, acc, 0, 0, 0);
        acc = __builtin_amdgcn_mfma_f32_16x16x32_bf16(af[t4*2+1], b1, acc, 0, 0, 0);
        int pbase = (mtb + t4) * 16 + q * 4;
        #pragma unroll
        for (int reg = 0; reg < 4; reg++) {
          int row = pbase + reg;
          XB[row * XS + ((g ^ (row & 7)) * 8 + off)] = f2bf(fmaxf(acc[reg] + bias, 0.f));
        }
      }
    }
  }
  // ---- layer4: 64 -> 16 -> regs ----
  f32x4 acc4[4];
  float bias4;
  {
    bf16x8 af[8];
    #pragma unroll
    for (int t4 = 0; t4 < 4; t4++) {
      int row = (mtb + t4) * 16 + m15;
      #pragma unroll
      for (int kc = 0; kc < 2; kc++)
        af[t4*2+kc] = *(const bf16x8*)(XB + row * XS + (((kc*4 + q) ^ (row & 7)) * 8));
    }
    bf16x8 b0 = *(const bf16x8*)(VP + VP3OFF + 0 * 512 + (q * 16 + m15) * 8);
    bf16x8 b1 = *(const bf16x8*)(VP + VP3OFF + 1 * 512 + (q * 16 + m15) * 8);
    bias4 = w[WR_C3 + m15];
    #pragma unroll
    for (int t4 = 0; t4 < 4; t4++) {
      f32x4 acc = (f32x4){0.f,0.f,0.f,0.f};
      acc = __builtin_amdgcn_mfma_f32_16x16x32_bf16(af[t4*2+0], b0, acc, 0, 0, 0);
      acc = __builtin_amdgcn_mfma_f32_16x16x32_bf16(af[t4*2+1], b1, acc, 0, 0, 0);
      acc4[t4] = acc;
    }
  }
  __syncthreads();   // RRB aliases XB across wave rows
  float* RRB = (float*)XB;
  #pragma unroll
  for (int t4 = 0; t4 < 4; t4++) {
    int pbase = (mtb + t4) * 16 + q * 4;
    #pragma unroll
    for (int reg = 0; reg < 4; reg++)
      RRB[(pbase + reg) * RSTR + m15] = acc4[t4][reg] + bias4;
  }
  float rr[16];
  {
    const float4* rp = (const float4*)(RRB + tid * RSTR);
    float4 v0 = rp[0], v1 = rp[1], v2 = rp[2], v3 = rp[3];
    rr[0]=v0.x; rr[1]=v0.y; rr[2]=v0.z; rr[3]=v0.w;
    rr[4]=v1.x; rr[5]=v1.y; rr[6]=v1.z; rr[7]=v1.w;
    rr[8]=v2.x; rr[9]=v2.y; rr[10]=v2.z; rr[11]=v2.w;
    rr[12]=v3.x; rr[13]=v3.y; rr[14]=v3.z; rr[15]=v3.w;
  }
  size_t base = (size_t)i * 8192 + (size_t)k * 16;
  float mv[16];
  load16f(mtr, base, f32, mv);
  if (f32) {
    float4* op = (float4*)((float*)out + base);
    op[0] = make_float4(mv[0]+rr[0],  mv[1]+rr[1],  mv[2]+rr[2],  mv[3]+rr[3]);
    op[1] = make_float4(mv[4]+rr[4],  mv[5]+rr[5],  mv[6]+rr[6],  mv[7]+rr[7]);
    op[2] = make_float4(mv[8]+rr[8],  mv[9]+rr[9],  mv[10]+rr[10],mv[11]+rr[11]);
    op[3] = make_float4(mv[12]+rr[12],mv[13]+rr[13],mv[14]+rr[14],mv[15]+rr[15]);
  } else {
    unsigned pw[8];
    #pragma unroll
    for (int q2 = 0; q2 < 8; q2++)
      pw[q2] = pack2(mv[2*q2] + rr[2*q2], mv[2*q2+1] + rr[2*q2+1]);
    uint4* op = (uint4*)((__hip_bfloat16*)out + base);
    op[0] = make_uint4(pw[0], pw[1], pw[2], pw[3]);
    op[1] = make_uint4(pw[4], pw[5], pw[6], pw[7]);
  }
}

// ================= fallback path (small ws) =================
__global__ void prep_weights(
  const void* __restrict__ W0, const void* __restrict__ b0,
  const void* __restrict__ W1, const void* __restrict__ b1,
  const void* __restrict__ W2, const void* __restrict__ b2,
  const void* __restrict__ W3, const void* __restrict__ b3,
  const void* __restrict__ V0, const void* __restrict__ c0,
  const void* __restrict__ V1, const void* __restrict__ c1,
  const void* __restrict__ V2, const void* __restrict__ c2,
  const void* __restrict__ V3, const void* __restrict__ c3,
  const void* __restrict__ L,  const void* __restrict__ Lb,
  const unsigned short* __restrict__ mtr_u16,
  int* __restrict__ flag, float* __restrict__ w)
{
  __shared__ float mx[256];
  int tid = threadIdx.x;
  float m = 0.f;
  for (int t = tid; t < 4096; t += 256) {
    float v = __uint_as_float(((unsigned)mtr_u16[t]) << 16);
    if (v != v) m = 3e38f;
    else m = fmaxf(m, fabsf(v));
  }
  mx[tid] = m;
  __syncthreads();
  for (int s = 128; s > 0; s >>= 1) {
    if (tid < s) mx[tid] = fmaxf(mx[tid], mx[tid + s]);
    __syncthreads();
  }
  const int f32 = (mx[0] > 1e6f) ? 1 : 0;
  if (blockIdx.x == 0 && tid == 0) flag[0] = f32;

  int g = blockIdx.x * blockDim.x + tid;
  int stride = gridDim.x * blockDim.x;
  auto cv = [&](const void* p, int off, int n){
    for (int i = g; i < n; i += stride) w[off + i] = ldelem(p, i, f32);
  };
  cv(W0, WR_W0, 512);  cv(b0, WR_B0, 64);
  cv(W1, WR_W1, 4096); cv(b1, WR_B1, 64);
  cv(W2, WR_W2, 4096); cv(b2, WR_B2, 64);
  cv(W3, WR_W3, 16384);cv(b3, WR_B3, 256);
  for (int idx = g; idx < 1024; idx += stride) {
    int j = idx >> 4, t = idx & 15;
    w[WR_V0T + idx] = ldelem(V0, t * 64 + j, f32);
  }
  cv(c0, WR_C0, 64);
  cv(V1, WR_V1, 4096); cv(c1, WR_C1, 64);
  cv(V2, WR_V2, 4096); cv(c2, WR_C2, 64);
  cv(V3, WR_V3, 1024); cv(c3, WR_C3, 16);
  cv(L,  WR_L,  256);  cv(Lb, WR_LB, 16);
}

__global__ void build_bins_basic(const int* __restrict__ ei,
                                 int* __restrict__ offs, int* __restrict__ sorted)
{
  __shared__ int cnt[512];
  __shared__ int cur[512];
  int tid = threadIdx.x;
  cnt[tid] = 0;
  __syncthreads();
  for (int e = tid; e < EE; e += 512) atomicAdd(&cnt[ei[EE + e]], 1);
  __syncthreads();
  int myc = cnt[tid];
  for (int off = 1; off < 512; off <<= 1) {
    int add = (tid >= off) ? cnt[tid - off] : 0;
    __syncthreads();
    cnt[tid] += add;
    __syncthreads();
  }
  int excl = cnt[tid] - myc;
  offs[tid] = excl;
  if (tid == 511) offs[512] = cnt[511];
  cur[tid] = excl;
  __syncthreads();
  for (int e = tid; e < EE; e += 512) {
    int d = ei[EE + e];
    sorted[atomicAdd(&cur[d], 1)] = e;
  }
}

__global__ __launch_bounds__(256) void edge_mlp_fb(
  const void* __restrict__ ea, const float* __restrict__ w,
  const int* __restrict__ flag, float* __restrict__ Fws)
{
  const int f32 = flag[0];
  const float* W0f = w + WR_W0; const float* b0f = w + WR_B0;
  const float* W1f = w + WR_W1; const float* b1f = w + WR_B1;
  const float* W2f = w + WR_W2; const float* b2f = w + WR_B2;
  const float* W3f = w + WR_W3; const float* b3f = w + WR_B3;
  int tid = threadIdx.x;
  int eg = tid >> 6, lane = tid & 63;
  int e = blockIdx.x * 4 + eg;
  __shared__ float shA[4][64];
  __shared__ float shB[4][64];
  float x[8];
  #pragma unroll
  for (int c = 0; c < 8; c++) x[c] = ldelem(ea, e * 8 + c, f32);
  float s = b0f[lane];
  #pragma unroll
  for (int c = 0; c < 8; c++) s += x[c] * W0f[c * 64 + lane];
  shA[eg][lane] = fmaxf(s, 0.f);
  __syncthreads();
  s = b1f[lane];
  #pragma unroll
  for (int c = 0; c < 64; c++) s += shA[eg][c] * W1f[c * 64 + lane];
  shB[eg][lane] = fmaxf(s, 0.f);
  __syncthreads();
  s = b2f[lane];
  #pragma unroll
  for (int c = 0; c < 64; c++) s += shB[eg][c] * W2f[c * 64 + lane];
  shA[eg][lane] = fmaxf(s, 0.f);
  __syncthreads();
  #pragma unroll
  for (int r2 = 0; r2 < 4; r2++) {
    int o = r2 * 64 + lane;
    float t = b3f[o];
    #pragma unroll
    for (int c = 0; c < 64; c++) t += shA[eg][c] * W3f[c * 256 + o];
    Fws[(size_t)e * 256 + o] = t;
  }
}

__global__ __launch_bounds__(256) void message_kernel_direct(
  const void* __restrict__ mtr, const int* __restrict__ ei,
  const float* __restrict__ Fws, const int* __restrict__ offs,
  const int* __restrict__ sorted, const int* __restrict__ flag,
  float* __restrict__ mtr1T)
{
  const int f32 = flag[0];
  int k = blockIdx.x;
  int i = blockIdx.y * 256 + threadIdx.x;
  float acc[16];
  #pragma unroll
  for (int t = 0; t < 16; t++) acc[t] = 0.f;
  int j0 = offs[k], j1 = offs[k + 1];
  for (int j = j0; j < j1; j++) {
    int e = __builtin_amdgcn_readfirstlane(sorted[j]);
    int s = __builtin_amdgcn_readfirstlane(ei[e]);
    float m[16];
    load16f(mtr, (size_t)i * 8192 + s * 16, f32, m);
    const float4* Fe = (const float4*)(Fws + (size_t)e * 256);
    #pragma unroll
    for (int c = 0; c < 16; c++) {
      float4 f0 = Fe[c*4+0], f1 = Fe[c*4+1], f2 = Fe[c*4+2], f3 = Fe[c*4+3];
      acc[0]  += m[c]*f0.x; acc[1]  += m[c]*f0.y; acc[2]  += m[c]*f0.z; acc[3]  += m[c]*f0.w;
      acc[4]  += m[c]*f1.x; acc[5]  += m[c]*f1.y; acc[6]  += m[c]*f1.z; acc[7]  += m[c]*f1.w;
      acc[8]  += m[c]*f2.x; acc[9]  += m[c]*f2.y; acc[10] += m[c]*f2.z; acc[11] += m[c]*f2.w;
      acc[12] += m[c]*f3.x; acc[13] += m[c]*f3.y; acc[14] += m[c]*f3.z; acc[15] += m[c]*f3.w;
    }
  }
  float4* op = (float4*)(mtr1T + (size_t)k * 8192 + i * 16);
  op[0] = make_float4(acc[0],  acc[1],  acc[2],  acc[3]);
  op[1] = make_float4(acc[4],  acc[5],  acc[6],  acc[7]);
  op[2] = make_float4(acc[8],  acc[9],  acc[10], acc[11]);
  op[3] = make_float4(acc[12], acc[13], acc[14], acc[15]);
}

__global__ __launch_bounds__(256, 4) void final_kernel_fb(
  const void* __restrict__ mtr, const float* __restrict__ w,
  const float* __restrict__ mtr1T, const int* __restrict__ flag,
  void* __restrict__ out)
{
  const int f32 = flag[0];
  __shared__ unsigned hbuf[32 * 256];
  int tid = threadIdx.x;
  int ti = blockIdx.x >> 5, tk = blockIdx.x & 31;
  int r = tid >> 4, c = tid & 15;
  int i = ti * 16 + r, k = tk * 16 + c;
  float scale = (i == k) ? 0.f : 0.0625f;
  float y[16];
  {
    float a[16], b[16];
    const float4* pa = (const float4*)(mtr1T + (size_t)k * 8192 + (size_t)i * 16);
    const float4* pb = (const float4*)(mtr1T + (size_t)i * 8192 + (size_t)k * 16);
    #pragma unroll
    for (int q = 0; q < 4; q++) {
      float4 va = pa[q], vb = pb[q];
      a[q*4+0]=va.x*scale; a[q*4+1]=va.y*scale; a[q*4+2]=va.z*scale; a[q*4+3]=va.w*scale;
      b[q*4+0]=vb.x*scale; b[q*4+1]=vb.y*scale; b[q*4+2]=vb.z*scale; b[q*4+3]=vb.w*scale;
    }
    const float* Lf  = w + WR_L;
    const float* Lbf = w + WR_LB;
    #pragma unroll
    for (int t = 0; t < 16; t++) y[t] = a[t] + Lbf[t];
    #pragma unroll
    for (int cc = 0; cc < 16; cc++) {
      #pragma unroll
      for (int t = 0; t < 16; t++) y[t] += b[cc] * Lf[cc * 16 + t];
    }
  }
  {
    const float* V0t = w + WR_V0T; const float* c0f = w + WR_C0;
    for (int m = 0; m < 32; m++) {
      float s0 = c0f[2*m], s1 = c0f[2*m+1];
      #pragma unroll
      for (int t = 0; t < 16; t++) {
        s0 += y[t] * V0t[(2*m) * 16 + t];
        s1 += y[t] * V0t[(2*m+1) * 16 + t];
      }
      hbuf[m * 256 + tid] = pack2(fmaxf(s0, 0.f), fmaxf(s1, 0.f));
    }
  }
  #pragma unroll
  for (int lyr = 0; lyr < 2; lyr++) {
    const float* Vf = w + (lyr ? WR_V2 : WR_V1);
    const float* cf = w + (lyr ? WR_C2 : WR_C1);
    unsigned held[16];
    #pragma unroll
    for (int pass = 0; pass < 2; pass++) {
      float s[32];
      #pragma unroll
      for (int jj = 0; jj < 32; jj++) s[jj] = cf[pass * 32 + jj];
      for (int m = 0; m < 32; m++) {
        unsigned hu = hbuf[m * 256 + tid];
        float h0 = bflo(hu), h1 = bfhi(hu);
        #pragma unroll
        for (int jj = 0; jj < 32; jj++)
          s[jj] += h0 * Vf[(2*m) * 64 + pass*32 + jj] + h1 * Vf[(2*m+1) * 64 + pass*32 + jj];
      }
      if (pass == 0) {
        #pragma unroll
        for (int q = 0; q < 16; q++) held[q] = pack2(fmaxf(s[2*q], 0.f), fmaxf(s[2*q+1], 0.f));
      } else {
        #pragma unroll
        for (int q = 0; q < 16; q++) hbuf[q * 256 + tid] = held[q];
        #pragma unroll
        for (int q = 0; q < 16; q++) hbuf[(16 + q) * 256 + tid] = pack2(fmaxf(s[2*q], 0.f), fmaxf(s[2*q+1], 0.f));
      }
    }
  }
  float rr[16];
  {
    const float* V3f = w + WR_V3; const float* c3f = w + WR_C3;
    #pragma unroll
    for (int t = 0; t < 16; t++) rr[t] = c3f[t];
    for (int m = 0; m < 32; m++) {
      unsigned hu = hbuf[m * 256 + tid];
      float h0 = bflo(hu), h1 = bfhi(hu);
      #pragma unroll
      for (int t = 0; t < 16; t++)
        rr[t] += h0 * V3f[(2*m) * 16 + t] + h1 * V3f[(2*m+1) * 16 + t];
    }
  }
  size_t base = (size_t)i * 8192 + (size_t)k * 16;
  float mv[16];
  load16f(mtr, base, f32, mv);
  if (f32) {
    float4* op = (float4*)((float*)out + base);
    op[0] = make_float4(mv[0]+rr[0],  mv[1]+rr[1],  mv[2]+rr[2],  mv[3]+rr[3]);
    op[1] = make_float4(mv[4]+rr[4],  mv[5]+rr[5],  mv[6]+rr[6],  mv[7]+rr[7]);
    op[2] = make_float4(mv[8]+rr[8],  mv[9]+rr[9],  mv[10]+rr[10],mv[11]+rr[11]);
    op[3] = make_float4(mv[12]+rr[12],mv[13]+rr[13],mv[14]+rr[14],mv[15]+rr[15]);
  } else {
    unsigned pw[8];
    #pragma unroll
    for (int q = 0; q < 8; q++)
      pw[q] = pack2(mv[2*q] + rr[2*q], mv[2*q+1] + rr[2*q+1]);
    uint4* op = (uint4*)((__hip_bfloat16*)out + base);
    op[0] = make_uint4(pw[0], pw[1], pw[2], pw[3]);
    op[1] = make_uint4(pw[4], pw[5], pw[6], pw[7]);
  }
}

extern "C" void kernel_launch(void* const* d_in, const int* in_sizes, int n_in,
                              void* d_out, int out_size, void* d_ws, size_t ws_size,
                              hipStream_t stream)
{
  const void* mtr = d_in[0];
  const void* ea  = d_in[1];
  const int*  ei  = (const int*)d_in[2];

  float* ws    = (float*)d_ws;
  float* Fws   = ws + OFF_F;
  float* mtr1T = ws + OFF_MTR1;
  __hip_bfloat16* mtr1B = (__hip_bfloat16*)(ws + OFF_MTR1);
  float* w     = ws + OFF_W;
  int* offs    = (int*)(ws + OFF_OFFS);
  int* sorted  = (int*)(ws + OFF_SORTED);
  int* flag    = (int*)(ws + OFF_FLAG);
  __hip_bfloat16* mtrT = (__hip_bfloat16*)(ws + OFF_MTRT);
  int* offsP   = (int*)(ws + OFF_OFFSP);
  unsigned* packP = (unsigned*)(ws + OFF_PACKP);
  unsigned short* Fpack = (unsigned short*)(ws + OFF_FPACK);
  unsigned short* VP    = (unsigned short*)(ws + OFF_VPACK);

  if (ws_size >= WS_FULL2_BYTES) {
    prep_all<<<1573, 512, 0, stream>>>(
        mtr, ea, ei,
        d_in[3], d_in[4], d_in[5], d_in[6], d_in[7], d_in[8], d_in[9], d_in[10],
        d_in[11], d_in[12], d_in[13], d_in[14], d_in[15], d_in[16], d_in[17], d_in[18],
        d_in[19], d_in[20],
        flag, w, VP, offsP, packP, Fpack, mtrT);
    dim3 gmsg(512, 4);
    message_mfma2<<<gmsg, 256, 0, stream>>>(mtrT, Fpack, offsP, packP, mtr1B);
    final_mfma<<<1024, 256, 0, stream>>>(mtr, w, mtr1B, flag, VP, d_out);
  } else {
    prep_weights<<<32, 256, 0, stream>>>(d_in[3], d_in[4], d_in[5], d_in[6],
                                         d_in[7], d_in[8], d_in[9], d_in[10],
                                         d_in[11], d_in[12], d_in[13], d_in[14],
                                         d_in[15], d_in[16], d_in[17], d_in[18],
                                         d_in[19], d_in[20],
                                         (const unsigned short*)mtr, flag, w);
    build_bins_basic<<<1, 512, 0, stream>>>(ei, offs, sorted);
    edge_mlp_fb<<<EE / 4, 256, 0, stream>>>(ea, w, flag, Fws);
    dim3 gmsg(512, 2);
    message_kernel_direct<<<gmsg, 256, 0, stream>>>(mtr, ei, Fws, offs, sorted, flag, mtr1T);
    final_kernel_fb<<<1024, 256, 0, stream>>>(mtr, w, mtr1T, flag, d_out);
  }
}

// Round 9
// 183.509 us; speedup vs baseline: 1.1674x; 1.0854x over previous
//
#include <hip/hip_runtime.h>
#include <hip/hip_bf16.h>

#define NN 512
#define EE 8192

// ---- workspace layout (float offsets) ----
#define OFF_F     0u
#define OFF_MTR1  2097152u      // full path: N*N*16 bf16 (mtr1B) ; fallback: fp32 mtr1T
#define OFF_W     6291456u
#define WR_W0   0
#define WR_B0   512
#define WR_W1   576
#define WR_B1   4672
#define WR_W2   4736
#define WR_B2   8832
#define WR_W3   8896
#define WR_B3   25280
#define WR_V0T  25536
#define WR_C0   26560
#define WR_V1   26624
#define WR_C1   30720
#define WR_V2   30784
#define WR_C2   34880
#define WR_V3   34944
#define WR_C3   35968
#define WR_L    35984
#define WR_LB   36240
#define W_TOTAL 36256
#define OFF_OFFS    (OFF_W + W_TOTAL)
#define OFF_SORTED  (OFF_OFFS + 513)
#define OFF_FLAG    (OFF_SORTED + EE)
#define OFF_MTRT    6336420u
#define OFF_OFFSP   8433572u
#define OFF_PACKP   8434085u
#define OFF_FPACK   8442792u
#define OFF_VPACK   9491496u
#define WS_NEED_BYTES  ((size_t)(OFF_MTRT  + 2097152u) * 4u)
#define WS_FULL2_BYTES ((size_t)(OFF_VPACK + 5632u) * 4u)

#define VP0OFF 0
#define VP1OFF 2048
#define VP2OFF 6144
#define VP3OFF 10240

#define XS   64   // XB row stride (bf16 units) = 128 B; 256 rows = 32768 B
#define RSTR 20   // RRB row stride, f32

typedef __attribute__((ext_vector_type(8))) short bf16x8;
typedef __attribute__((ext_vector_type(4))) float f32x4;

__device__ __forceinline__ float bflo(unsigned u){ return __uint_as_float(u << 16); }
__device__ __forceinline__ float bfhi(unsigned u){ return __uint_as_float(u & 0xffff0000u); }
__device__ __forceinline__ unsigned short f2bf(float f){
  __hip_bfloat16 h = __float2bfloat16(f);
  union { __hip_bfloat16 hh; unsigned short ss; } u;
  u.hh = h; return u.ss;
}
__device__ __forceinline__ unsigned pack2(float a, float b){
  return (unsigned)f2bf(a) | ((unsigned)f2bf(b) << 16);
}
__device__ __forceinline__ float cvt(float v){ return v; }
__device__ __forceinline__ float cvt(__hip_bfloat16 v){ return __bfloat162float(v); }

__device__ __forceinline__ void load16f(const void* base, size_t eoff, int f32, float m[16]) {
  if (f32) {
    const float4* p = (const float4*)((const float*)base + eoff);
    float4 a = p[0], b = p[1], c = p[2], d = p[3];
    m[0]=a.x; m[1]=a.y; m[2]=a.z; m[3]=a.w;
    m[4]=b.x; m[5]=b.y; m[6]=b.z; m[7]=b.w;
    m[8]=c.x; m[9]=c.y; m[10]=c.z; m[11]=c.w;
    m[12]=d.x; m[13]=d.y; m[14]=d.z; m[15]=d.w;
  } else {
    const uint4* p = (const uint4*)((const __hip_bfloat16*)base + eoff);
    uint4 u0 = p[0], u1 = p[1];
    m[0]=bflo(u0.x);  m[1]=bfhi(u0.x);  m[2]=bflo(u0.y);  m[3]=bfhi(u0.y);
    m[4]=bflo(u0.z);  m[5]=bfhi(u0.z);  m[6]=bflo(u0.w);  m[7]=bfhi(u0.w);
    m[8]=bflo(u1.x);  m[9]=bfhi(u1.x);  m[10]=bflo(u1.y); m[11]=bfhi(u1.y);
    m[12]=bflo(u1.z); m[13]=bfhi(u1.z); m[14]=bflo(u1.w); m[15]=bfhi(u1.w);
  }
}

__device__ __forceinline__ float ldelem(const void* p, int idx, int f32) {
  return f32 ? ((const float*)p)[idx]
             : __bfloat162float(((const __hip_bfloat16*)p)[idx]);
}

__device__ __forceinline__ int detect_f32_local(const unsigned short* mtr_u16, float* red) {
  int tid = threadIdx.x;
  float m = 0.f;
  for (int t = tid; t < 4096; t += 512) {
    float v = __uint_as_float(((unsigned)mtr_u16[t]) << 16);
    if (v != v) m = 3e38f;
    else m = fmaxf(m, fabsf(v));
  }
  red[tid] = m;
  __syncthreads();
  for (int s = 256; s > 0; s >>= 1) {
    if (tid < s) red[tid] = fmaxf(red[tid], red[tid + s]);
    __syncthreads();
  }
  float mx = red[0];
  __syncthreads();
  return (mx > 1e6f) ? 1 : 0;
}

template <typename T>
__device__ void edge_body(const T* __restrict__ ea,
                          const T* __restrict__ W0, const T* __restrict__ b0,
                          const T* __restrict__ W1, const T* __restrict__ b1,
                          const T* __restrict__ W2, const T* __restrict__ b2,
                          const T* __restrict__ W3, const T* __restrict__ b3,
                          int e, int eg, int lane,
                          float (*shA)[64], float (*shB)[64],
                          unsigned short* __restrict__ Fpack)
{
  float x[8];
  #pragma unroll
  for (int c = 0; c < 8; c++) x[c] = cvt(ea[(size_t)e * 8 + c]);

  float s = cvt(b0[lane]);
  #pragma unroll
  for (int c = 0; c < 8; c++) s += x[c] * cvt(W0[c * 64 + lane]);
  shA[eg][lane] = fmaxf(s, 0.f);
  __syncthreads();

  s = cvt(b1[lane]);
  #pragma unroll
  for (int c = 0; c < 64; c++) s += shA[eg][c] * cvt(W1[c * 64 + lane]);
  shB[eg][lane] = fmaxf(s, 0.f);
  __syncthreads();

  s = cvt(b2[lane]);
  #pragma unroll
  for (int c = 0; c < 64; c++) s += shB[eg][c] * cvt(W2[c * 64 + lane]);
  shA[eg][lane] = fmaxf(s, 0.f);
  __syncthreads();

  int quad = lane >> 4, tt = lane & 15;
  #pragma unroll
  for (int r = 0; r < 4; r++) {
    int o = r * 64 + lane;
    float t = cvt(b3[o]);
    #pragma unroll
    for (int c = 0; c < 64; c++) t += shA[eg][c] * cvt(W3[c * 256 + o]);
    int cc = r * 4 + quad;
    Fpack[(size_t)e * 256 + (cc >> 3) * 128 + tt * 8 + (cc & 7)] = f2bf(t);
  }
}

// ---- K1: fused prep (roles by blockIdx.x) ----
__global__ __launch_bounds__(512) void prep_all(
  const void* __restrict__ mtr, const void* __restrict__ ea, const int* __restrict__ ei,
  const void* __restrict__ W0, const void* __restrict__ b0,
  const void* __restrict__ W1, const void* __restrict__ b1,
  const void* __restrict__ W2, const void* __restrict__ b2,
  const void* __restrict__ W3, const void* __restrict__ b3,
  const void* __restrict__ V0, const void* __restrict__ c0,
  const void* __restrict__ V1, const void* __restrict__ c1,
  const void* __restrict__ V2, const void* __restrict__ c2,
  const void* __restrict__ V3, const void* __restrict__ c3,
  const void* __restrict__ L,  const void* __restrict__ Lb,
  int* __restrict__ flag, float* __restrict__ w, unsigned short* __restrict__ VP,
  int* __restrict__ offsP, unsigned* __restrict__ packP,
  unsigned short* __restrict__ Fpack, __hip_bfloat16* __restrict__ mtrT)
{
  __shared__ __attribute__((aligned(16))) char smem_raw[8192];
  int tid = threadIdx.x;
  int bid = blockIdx.x;
  const int f32 = detect_f32_local((const unsigned short*)mtr, (float*)smem_raw);

  if (bid == 0) {
    int* cnt  = (int*)smem_raw;
    int* pcs  = cnt + 512;
    int* curP = pcs + 512;
    cnt[tid] = 0;
    if (tid == 0) flag[0] = f32;
    __syncthreads();
    for (int e = tid; e < EE; e += 512) atomicAdd(&cnt[ei[EE + e]], 1);
    __syncthreads();
    int myc = cnt[tid];
    int myp = (myc + 1) & ~1;
    pcs[tid] = myp;
    __syncthreads();
    for (int off = 1; off < 512; off <<= 1) {
      int b = (tid >= off) ? pcs[tid - off] : 0;
      __syncthreads();
      pcs[tid] += b;
      __syncthreads();
    }
    int excP = pcs[tid] - myp;
    offsP[tid] = excP;
    if (tid == 511) offsP[512] = pcs[511];
    curP[tid] = excP;
    if (myc & 1) packP[excP + myc] = EE;
    __syncthreads();
    for (int e = tid; e < EE; e += 512) {
      int d = ei[EE + e];
      int s = ei[e];
      packP[atomicAdd(&curP[d], 1)] = (unsigned)e | ((unsigned)s << 14);
    }
    unsigned* fz = (unsigned*)(Fpack + (size_t)EE * 256);
    for (int i2 = tid; i2 < 128; i2 += 512) fz[i2] = 0u;
  } else if (bid < 33) {
    int g = (bid - 1) * 512 + tid;
    const int stride = 32 * 512;
    auto cv = [&](const void* p, int off, int n){
      for (int i = g; i < n; i += stride) w[off + i] = ldelem(p, i, f32);
    };
    cv(W0, WR_W0, 512);  cv(b0, WR_B0, 64);
    cv(W1, WR_W1, 4096); cv(b1, WR_B1, 64);
    cv(W2, WR_W2, 4096); cv(b2, WR_B2, 64);
    cv(W3, WR_W3, 16384);cv(b3, WR_B3, 256);
    for (int idx = g; idx < 1024; idx += stride) {
      int j = idx >> 4, t = idx & 15;
      w[WR_V0T + idx] = ldelem(V0, t * 64 + j, f32);
    }
    cv(c0, WR_C0, 64);
    cv(V1, WR_V1, 4096); cv(c1, WR_C1, 64);
    cv(V2, WR_V2, 4096); cv(c2, WR_C2, 64);
    cv(V3, WR_V3, 1024); cv(c3, WR_C3, 16);
    cv(L,  WR_L,  256);  cv(Lb, WR_LB, 16);
  } else if (bid < 37) {
    int g = (bid - 33) * 512 + tid;
    const int stride = 4 * 512;
    for (int idx = g; idx < 2048; idx += stride) {
      int j = idx & 7, lp = (idx >> 3) & 63, nt = idx >> 9;
      int nn = lp & 15, qq = lp >> 4;
      int kk = qq * 8 + j;
      float v = (kk < 16) ? ldelem(V0, kk * 64 + nt * 16 + nn, f32) : 0.f;
      VP[VP0OFF + idx] = f2bf(v);
    }
    for (int idx = g; idx < 4096; idx += stride) {
      int j = idx & 7, lp = (idx >> 3) & 63, tile = idx >> 9;
      int nn = lp & 15, qq = lp >> 4;
      int kc = tile >> 2, nt = tile & 3;
      int kk = kc * 32 + qq * 8 + j;
      VP[VP1OFF + idx] = f2bf(ldelem(V1, kk * 64 + nt * 16 + nn, f32));
      VP[VP2OFF + idx] = f2bf(ldelem(V2, kk * 64 + nt * 16 + nn, f32));
    }
    for (int idx = g; idx < 1024; idx += stride) {
      int j = idx & 7, lp = (idx >> 3) & 63, kc = idx >> 9;
      int nn = lp & 15, qq = lp >> 4;
      int kk = kc * 32 + qq * 8 + j;
      VP[VP3OFF + idx] = f2bf(ldelem(V3, kk * 16 + nn, f32));
    }
  } else if (bid < 549) {
    int s = bid - 37;
    int i = tid;
    float m[16];
    load16f(mtr, (size_t)i * 8192 + (size_t)s * 16, f32, m);
    unsigned pw[8];
    #pragma unroll
    for (int q = 0; q < 8; q++) pw[q] = pack2(m[2*q], m[2*q+1]);
    uint4* op = (uint4*)(mtrT + (size_t)s * 8192 + (size_t)i * 16);
    op[0] = make_uint4(pw[0], pw[1], pw[2], pw[3]);
    op[1] = make_uint4(pw[4], pw[5], pw[6], pw[7]);
  } else {
    int eg = tid >> 6, lane = tid & 63;
    int e = (bid - 549) * 8 + eg;
    float (*shA)[64] = (float(*)[64])smem_raw;
    float (*shB)[64] = (float(*)[64])(smem_raw + 2048);
    if (f32)
      edge_body<float>((const float*)ea,
        (const float*)W0, (const float*)b0, (const float*)W1, (const float*)b1,
        (const float*)W2, (const float*)b2, (const float*)W3, (const float*)b3,
        e, eg, lane, shA, shB, Fpack);
    else
      edge_body<__hip_bfloat16>((const __hip_bfloat16*)ea,
        (const __hip_bfloat16*)W0, (const __hip_bfloat16*)b0,
        (const __hip_bfloat16*)W1, (const __hip_bfloat16*)b1,
        (const __hip_bfloat16*)W2, (const __hip_bfloat16*)b2,
        (const __hip_bfloat16*)W3, (const __hip_bfloat16*)b3,
        e, eg, lane, shA, shB, Fpack);
  }
}

// ---- K2: message via MFMA; grid (512 k, 4 i-quarters); bf16 mtr1 output ----
__global__ __launch_bounds__(256) void message_mfma2(
  const __hip_bfloat16* __restrict__ mtrT,
  const unsigned short* __restrict__ Fpack,
  const int* __restrict__ offsP, const unsigned* __restrict__ packP,
  __hip_bfloat16* __restrict__ mtr1B)
{
  int k = blockIdx.x;
  int tid = threadIdx.x;
  int wave = tid >> 6, lane = tid & 63;
  int n = lane & 15, quad = lane >> 4;
  int qh = quad >> 1, qq = quad & 1;
  int ibase = blockIdx.y * 128 + wave * 32;
  int j0 = offsP[k], j1 = offsP[k + 1];

  f32x4 acc0 = (f32x4){0.f,0.f,0.f,0.f};
  f32x4 acc1 = (f32x4){0.f,0.f,0.f,0.f};

  bf16x8 bfrag, af0, af1;
  auto loadfr = [&](int j) {
    unsigned p1 = __builtin_amdgcn_readfirstlane(packP[j]);
    unsigned p2 = __builtin_amdgcn_readfirstlane(packP[j + 1]);
    unsigned pv = qh ? p2 : p1;
    int es = (int)(pv & 0x3FFFu);
    int ss = (int)(pv >> 14);
    bfrag = *(const bf16x8*)(Fpack + (size_t)es * 256 + (qq * 16 + n) * 8);
    const __hip_bfloat16* ab = mtrT + (size_t)ss * 8192 + qq * 8;
    af0 = *(const bf16x8*)(ab + (size_t)(ibase + 0 * 16 + n) * 16);
    af1 = *(const bf16x8*)(ab + (size_t)(ibase + 1 * 16 + n) * 16);
  };
  if (j0 < j1) loadfr(j0);
  for (int j = j0; j < j1; j += 2) {
    bf16x8 bc = bfrag, a0 = af0, a1 = af1;
    if (j + 2 < j1) loadfr(j + 2);
    acc0 = __builtin_amdgcn_mfma_f32_16x16x32_bf16(a0, bc, acc0, 0, 0, 0);
    acc1 = __builtin_amdgcn_mfma_f32_16x16x32_bf16(a1, bc, acc1, 0, 0, 0);
  }

  __hip_bfloat16* obase = mtr1B + (size_t)k * 8192;
  #pragma unroll
  for (int reg = 0; reg < 4; reg++) {
    int r0 = ibase + 0 * 16 + quad * 4 + reg;
    int r1 = ibase + 1 * 16 + quad * 4 + reg;
    obase[(size_t)r0 * 16 + n] = __float2bfloat16(acc0[reg]);
    obase[(size_t)r1 * 16 + n] = __float2bfloat16(acc1[reg]);
  }
}

// ---- K3: final via MFMA; 512 threads / 8 waves, 2 m-tiles per wave ----
// Half the per-wave chain vs 256-thread version; 32 KB LDS -> up to 4 blk/CU
// = 32 waves/CU. Plain launch_bounds: (256,5)/(256,4) variants spilled
// (R7: WRITE 84 MB, R8: 45 MB vs 16.4 actual).
__global__ __launch_bounds__(512) void final_mfma(
  const void* __restrict__ mtr, const float* __restrict__ w,
  const __hip_bfloat16* __restrict__ mtr1B, const int* __restrict__ flag,
  const unsigned short* __restrict__ VP, void* __restrict__ out)
{
  const int f32 = flag[0];
  __shared__ __attribute__((aligned(16))) unsigned short XB[256 * XS];  // 32768 B
  int tid = threadIdx.x;
  int ti = blockIdx.x >> 5, tk = blockIdx.x & 31;
  int i0 = ti * 16, k0 = tk * 16;

  // ---- stage A (k-rows x i-cols) and B (i-rows x k-cols), coalesced ----
  {
    int row = tid >> 5, off = tid & 31;
    const uint4* ga = (const uint4*)(mtr1B + (size_t)(k0 + row) * 8192 + (size_t)i0 * 16);
    const uint4* gb = (const uint4*)(mtr1B + (size_t)(i0 + row) * 8192 + (size_t)k0 * 16);
    ((uint4*)(XB + row * 264))[off] = ga[off];
    ((uint4*)(XB + 4224 + row * 264))[off] = gb[off];
  }
  __syncthreads();

  // ---- y: 2 threads per position, 8 channels each ----
  int pos = tid >> 1, half = tid & 1;
  int r = pos >> 4, c = pos & 15;
  int i = i0 + r, k = k0 + c;
  float scale = (i == k) ? 0.f : 0.0625f;

  float y[8];
  {
    const uint4* ap = (const uint4*)(XB + c * 264 + r * 16);
    const uint4* bp = (const uint4*)(XB + 4224 + r * 264 + c * 16);
    uint4 av = ap[half];
    uint4 bv0 = bp[0], bv1 = bp[1];
    float a_[8], b_[16];
    a_[0]=bflo(av.x); a_[1]=bfhi(av.x); a_[2]=bflo(av.y); a_[3]=bfhi(av.y);
    a_[4]=bflo(av.z); a_[5]=bfhi(av.z); a_[6]=bflo(av.w); a_[7]=bfhi(av.w);
    b_[0]=bflo(bv0.x);  b_[1]=bfhi(bv0.x);  b_[2]=bflo(bv0.y);  b_[3]=bfhi(bv0.y);
    b_[4]=bflo(bv0.z);  b_[5]=bfhi(bv0.z);  b_[6]=bflo(bv0.w);  b_[7]=bfhi(bv0.w);
    b_[8]=bflo(bv1.x);  b_[9]=bfhi(bv1.x);  b_[10]=bflo(bv1.y); b_[11]=bfhi(bv1.y);
    b_[12]=bflo(bv1.z); b_[13]=bfhi(bv1.z); b_[14]=bflo(bv1.w); b_[15]=bfhi(bv1.w);
    const float* Lf  = w + WR_L;
    const float* Lbf = w + WR_LB;
    int tb = half * 8;
    #pragma unroll
    for (int t = 0; t < 8; t++) y[t] = a_[t] * scale + Lbf[tb + t];
    #pragma unroll
    for (int cc = 0; cc < 16; cc++) {
      float bs = b_[cc] * scale;
      #pragma unroll
      for (int t = 0; t < 8; t++) y[t] += bs * Lf[cc * 16 + tb + t];
    }
  }
  __syncthreads();   // tiles dead; region becomes swizzled XB

  // ---- stage y: logical 16B-group g at phys g ^ (pos&7) ----
  {
    unsigned sw = pos & 7;
    uint4 d = make_uint4(pack2(y[0],y[1]), pack2(y[2],y[3]),
                         pack2(y[4],y[5]), pack2(y[6],y[7]));
    uint4 z = make_uint4(0,0,0,0);
    uint4* rowp = (uint4*)(XB + pos * XS);
    rowp[half ^ sw] = d;          // data group (0 or 1)
    rowp[(2 + half) ^ sw] = z;    // zero pad group (2 or 3)
  }

  int wave = tid >> 6, lane = tid & 63;
  int m15 = lane & 15, q = lane >> 4;
  int mtb = wave * 2;   // 2 m-tiles per wave; rows 32w..32w+31 wave-private

  // ---- layer1: 16(pad32) -> 64 ----
  {
    bf16x8 af[2];
    #pragma unroll
    for (int t4 = 0; t4 < 2; t4++) {
      int row = (mtb + t4) * 16 + m15;
      af[t4] = *(const bf16x8*)(XB + row * XS + ((q ^ (row & 7)) * 8));
    }
    #pragma unroll
    for (int nt = 0; nt < 4; nt++) {
      bf16x8 bf_ = *(const bf16x8*)(VP + VP0OFF + nt * 512 + (q * 16 + m15) * 8);
      float bias = w[WR_C0 + nt * 16 + m15];
      int g = nt * 2 + (m15 >> 3), off = m15 & 7;
      #pragma unroll
      for (int t4 = 0; t4 < 2; t4++) {
        f32x4 acc = (f32x4){0.f,0.f,0.f,0.f};
        acc = __builtin_amdgcn_mfma_f32_16x16x32_bf16(af[t4], bf_, acc, 0, 0, 0);
        int pbase = (mtb + t4) * 16 + q * 4;
        #pragma unroll
        for (int reg = 0; reg < 4; reg++) {
          int row = pbase + reg;
          XB[row * XS + ((g ^ (row & 7)) * 8 + off)] = f2bf(fmaxf(acc[reg] + bias, 0.f));
        }
      }
    }
  }
  // ---- layers 2,3: 64 -> 64, in-place (frag preload) ----
  #pragma unroll
  for (int layer = 0; layer < 2; layer++) {
    int vpo  = layer ? VP2OFF : VP1OFF;
    int wrc  = layer ? WR_C2  : WR_C1;
    bf16x8 af[4];
    #pragma unroll
    for (int t4 = 0; t4 < 2; t4++) {
      int row = (mtb + t4) * 16 + m15;
      #pragma unroll
      for (int kc = 0; kc < 2; kc++)
        af[t4*2+kc] = *(const bf16x8*)(XB + row * XS + (((kc*4 + q) ^ (row & 7)) * 8));
    }
    #pragma unroll
    for (int nt = 0; nt < 4; nt++) {
      bf16x8 b0 = *(const bf16x8*)(VP + vpo + (0 * 4 + nt) * 512 + (q * 16 + m15) * 8);
      bf16x8 b1 = *(const bf16x8*)(VP + vpo + (1 * 4 + nt) * 512 + (q * 16 + m15) * 8);
      float bias = w[wrc + nt * 16 + m15];
      int g = nt * 2 + (m15 >> 3), off = m15 & 7;
      #pragma unroll
      for (int t4 = 0; t4 < 2; t4++) {
        f32x4 acc = (f32x4){0.f,0.f,0.f,0.f};
        acc = __builtin_amdgcn_mfma_f32_16x16x32_bf16(af[t4*2+0], b0, acc, 0, 0, 0);
        acc = __builtin_amdgcn_mfma_f32_16x16x32_bf16(af[t4*2+1], b1, acc, 0, 0, 0);
        int pbase = (mtb + t4) * 16 + q * 4;
        #pragma unroll
        for (int reg = 0; reg < 4; reg++) {
          int row = pbase + reg;
          XB[row * XS + ((g ^ (row & 7)) * 8 + off)] = f2bf(fmaxf(acc[reg] + bias, 0.f));
        }
      }
    }
  }
  // ---- layer4: 64 -> 16 -> regs ----
  f32x4 acc4[2];
  float bias4;
  {
    bf16x8 af[4];
    #pragma unroll
    for (int t4 = 0; t4 < 2; t4++) {
      int row = (mtb + t4) * 16 + m15;
      #pragma unroll
      for (int kc = 0; kc < 2; kc++)
        af[t4*2+kc] = *(const bf16x8*)(XB + row * XS + (((kc*4 + q) ^ (row & 7)) * 8));
    }
    bf16x8 b0 = *(const bf16x8*)(VP + VP3OFF + 0 * 512 + (q * 16 + m15) * 8);
    bf16x8 b1 = *(const bf16x8*)(VP + VP3OFF + 1 * 512 + (q * 16 + m15) * 8);
    bias4 = w[WR_C3 + m15];
    #pragma unroll
    for (int t4 = 0; t4 < 2; t4++) {
      f32x4 acc = (f32x4){0.f,0.f,0.f,0.f};
      acc = __builtin_amdgcn_mfma_f32_16x16x32_bf16(af[t4*2+0], b0, acc, 0, 0, 0);
      acc = __builtin_amdgcn_mfma_f32_16x16x32_bf16(af[t4*2+1], b1, acc, 0, 0, 0);
      acc4[t4] = acc;
    }
  }
  __syncthreads();   // RRB aliases XB across wave rows
  float* RRB = (float*)XB;
  #pragma unroll
  for (int t4 = 0; t4 < 2; t4++) {
    int pbase = (mtb + t4) * 16 + q * 4;
    #pragma unroll
    for (int reg = 0; reg < 4; reg++)
      RRB[(pbase + reg) * RSTR + m15] = acc4[t4][reg] + bias4;
  }
  // readback + epilogue: wave-private rows (pos = tid>>1 in [32w,32w+32))
  float rr[8];
  {
    const float4* rp = (const float4*)(RRB + pos * RSTR + half * 8);
    float4 v0 = rp[0], v1 = rp[1];
    rr[0]=v0.x; rr[1]=v0.y; rr[2]=v0.z; rr[3]=v0.w;
    rr[4]=v1.x; rr[5]=v1.y; rr[6]=v1.z; rr[7]=v1.w;
  }
  size_t base = (size_t)i * 8192 + (size_t)k * 16 + half * 8;
  if (f32) {
    const float4* mp = (const float4*)((const float*)mtr + base);
    float4 m0 = mp[0], m1 = mp[1];
    float4* op = (float4*)((float*)out + base);
    op[0] = make_float4(m0.x+rr[0], m0.y+rr[1], m0.z+rr[2], m0.w+rr[3]);
    op[1] = make_float4(m1.x+rr[4], m1.y+rr[5], m1.z+rr[6], m1.w+rr[7]);
  } else {
    uint4 mu = *(const uint4*)((const __hip_bfloat16*)mtr + base);
    float mv[8];
    mv[0]=bflo(mu.x); mv[1]=bfhi(mu.x); mv[2]=bflo(mu.y); mv[3]=bfhi(mu.y);
    mv[4]=bflo(mu.z); mv[5]=bfhi(mu.z); mv[6]=bflo(mu.w); mv[7]=bfhi(mu.w);
    uint4* op = (uint4*)((__hip_bfloat16*)out + base);
    *op = make_uint4(pack2(mv[0]+rr[0], mv[1]+rr[1]), pack2(mv[2]+rr[2], mv[3]+rr[3]),
                     pack2(mv[4]+rr[4], mv[5]+rr[5]), pack2(mv[6]+rr[6], mv[7]+rr[7]));
  }
}

// ================= fallback path (small ws) =================
__global__ void prep_weights(
  const void* __restrict__ W0, const void* __restrict__ b0,
  const void* __restrict__ W1, const void* __restrict__ b1,
  const void* __restrict__ W2, const void* __restrict__ b2,
  const void* __restrict__ W3, const void* __restrict__ b3,
  const void* __restrict__ V0, const void* __restrict__ c0,
  const void* __restrict__ V1, const void* __restrict__ c1,
  const void* __restrict__ V2, const void* __restrict__ c2,
  const void* __restrict__ V3, const void* __restrict__ c3,
  const void* __restrict__ L,  const void* __restrict__ Lb,
  const unsigned short* __restrict__ mtr_u16,
  int* __restrict__ flag, float* __restrict__ w)
{
  __shared__ float mx[256];
  int tid = threadIdx.x;
  float m = 0.f;
  for (int t = tid; t < 4096; t += 256) {
    float v = __uint_as_float(((unsigned)mtr_u16[t]) << 16);
    if (v != v) m = 3e38f;
    else m = fmaxf(m, fabsf(v));
  }
  mx[tid] = m;
  __syncthreads();
  for (int s = 128; s > 0; s >>= 1) {
    if (tid < s) mx[tid] = fmaxf(mx[tid], mx[tid + s]);
    __syncthreads();
  }
  const int f32 = (mx[0] > 1e6f) ? 1 : 0;
  if (blockIdx.x == 0 && tid == 0) flag[0] = f32;

  int g = blockIdx.x * blockDim.x + tid;
  int stride = gridDim.x * blockDim.x;
  auto cv = [&](const void* p, int off, int n){
    for (int i = g; i < n; i += stride) w[off + i] = ldelem(p, i, f32);
  };
  cv(W0, WR_W0, 512);  cv(b0, WR_B0, 64);
  cv(W1, WR_W1, 4096); cv(b1, WR_B1, 64);
  cv(W2, WR_W2, 4096); cv(b2, WR_B2, 64);
  cv(W3, WR_W3, 16384);cv(b3, WR_B3, 256);
  for (int idx = g; idx < 1024; idx += stride) {
    int j = idx >> 4, t = idx & 15;
    w[WR_V0T + idx] = ldelem(V0, t * 64 + j, f32);
  }
  cv(c0, WR_C0, 64);
  cv(V1, WR_V1, 4096); cv(c1, WR_C1, 64);
  cv(V2, WR_V2, 4096); cv(c2, WR_C2, 64);
  cv(V3, WR_V3, 1024); cv(c3, WR_C3, 16);
  cv(L,  WR_L,  256);  cv(Lb, WR_LB, 16);
}

__global__ void build_bins_basic(const int* __restrict__ ei,
                                 int* __restrict__ offs, int* __restrict__ sorted)
{
  __shared__ int cnt[512];
  __shared__ int cur[512];
  int tid = threadIdx.x;
  cnt[tid] = 0;
  __syncthreads();
  for (int e = tid; e < EE; e += 512) atomicAdd(&cnt[ei[EE + e]], 1);
  __syncthreads();
  int myc = cnt[tid];
  for (int off = 1; off < 512; off <<= 1) {
    int add = (tid >= off) ? cnt[tid - off] : 0;
    __syncthreads();
    cnt[tid] += add;
    __syncthreads();
  }
  int excl = cnt[tid] - myc;
  offs[tid] = excl;
  if (tid == 511) offs[512] = cnt[511];
  cur[tid] = excl;
  __syncthreads();
  for (int e = tid; e < EE; e += 512) {
    int d = ei[EE + e];
    sorted[atomicAdd(&cur[d], 1)] = e;
  }
}

__global__ __launch_bounds__(256) void edge_mlp_fb(
  const void* __restrict__ ea, const float* __restrict__ w,
  const int* __restrict__ flag, float* __restrict__ Fws)
{
  const int f32 = flag[0];
  const float* W0f = w + WR_W0; const float* b0f = w + WR_B0;
  const float* W1f = w + WR_W1; const float* b1f = w + WR_B1;
  const float* W2f = w + WR_W2; const float* b2f = w + WR_B2;
  const float* W3f = w + WR_W3; const float* b3f = w + WR_B3;
  int tid = threadIdx.x;
  int eg = tid >> 6, lane = tid & 63;
  int e = blockIdx.x * 4 + eg;
  __shared__ float shA[4][64];
  __shared__ float shB[4][64];
  float x[8];
  #pragma unroll
  for (int c = 0; c < 8; c++) x[c] = ldelem(ea, e * 8 + c, f32);
  float s = b0f[lane];
  #pragma unroll
  for (int c = 0; c < 8; c++) s += x[c] * W0f[c * 64 + lane];
  shA[eg][lane] = fmaxf(s, 0.f);
  __syncthreads();
  s = b1f[lane];
  #pragma unroll
  for (int c = 0; c < 64; c++) s += shA[eg][c] * W1f[c * 64 + lane];
  shB[eg][lane] = fmaxf(s, 0.f);
  __syncthreads();
  s = b2f[lane];
  #pragma unroll
  for (int c = 0; c < 64; c++) s += shB[eg][c] * W2f[c * 64 + lane];
  shA[eg][lane] = fmaxf(s, 0.f);
  __syncthreads();
  #pragma unroll
  for (int r2 = 0; r2 < 4; r2++) {
    int o = r2 * 64 + lane;
    float t = b3f[o];
    #pragma unroll
    for (int c = 0; c < 64; c++) t += shA[eg][c] * W3f[c * 256 + o];
    Fws[(size_t)e * 256 + o] = t;
  }
}

__global__ __launch_bounds__(256) void message_kernel_direct(
  const void* __restrict__ mtr, const int* __restrict__ ei,
  const float* __restrict__ Fws, const int* __restrict__ offs,
  const int* __restrict__ sorted, const int* __restrict__ flag,
  float* __restrict__ mtr1T)
{
  const int f32 = flag[0];
  int k = blockIdx.x;
  int i = blockIdx.y * 256 + threadIdx.x;
  float acc[16];
  #pragma unroll
  for (int t = 0; t < 16; t++) acc[t] = 0.f;
  int j0 = offs[k], j1 = offs[k + 1];
  for (int j = j0; j < j1; j++) {
    int e = __builtin_amdgcn_readfirstlane(sorted[j]);
    int s = __builtin_amdgcn_readfirstlane(ei[e]);
    float m[16];
    load16f(mtr, (size_t)i * 8192 + s * 16, f32, m);
    const float4* Fe = (const float4*)(Fws + (size_t)e * 256);
    #pragma unroll
    for (int c = 0; c < 16; c++) {
      float4 f0 = Fe[c*4+0], f1 = Fe[c*4+1], f2 = Fe[c*4+2], f3 = Fe[c*4+3];
      acc[0]  += m[c]*f0.x; acc[1]  += m[c]*f0.y; acc[2]  += m[c]*f0.z; acc[3]  += m[c]*f0.w;
      acc[4]  += m[c]*f1.x; acc[5]  += m[c]*f1.y; acc[6]  += m[c]*f1.z; acc[7]  += m[c]*f1.w;
      acc[8]  += m[c]*f2.x; acc[9]  += m[c]*f2.y; acc[10] += m[c]*f2.z; acc[11] += m[c]*f2.w;
      acc[12] += m[c]*f3.x; acc[13] += m[c]*f3.y; acc[14] += m[c]*f3.z; acc[15] += m[c]*f3.w;
    }
  }
  float4* op = (float4*)(mtr1T + (size_t)k * 8192 + i * 16);
  op[0] = make_float4(acc[0],  acc[1],  acc[2],  acc[3]);
  op[1] = make_float4(acc[4],  acc[5],  acc[6],  acc[7]);
  op[2] = make_float4(acc[8],  acc[9],  acc[10], acc[11]);
  op[3] = make_float4(acc[12], acc[13], acc[14], acc[15]);
}

__global__ __launch_bounds__(256, 4) void final_kernel_fb(
  const void* __restrict__ mtr, const float* __restrict__ w,
  const float* __restrict__ mtr1T, const int* __restrict__ flag,
  void* __restrict__ out)
{
  const int f32 = flag[0];
  __shared__ unsigned hbuf[32 * 256];
  int tid = threadIdx.x;
  int ti = blockIdx.x >> 5, tk = blockIdx.x & 31;
  int r = tid >> 4, c = tid & 15;
  int i = ti * 16 + r, k = tk * 16 + c;
  float scale = (i == k) ? 0.f : 0.0625f;
  float y[16];
  {
    float a[16], b[16];
    const float4* pa = (const float4*)(mtr1T + (size_t)k * 8192 + (size_t)i * 16);
    const float4* pb = (const float4*)(mtr1T + (size_t)i * 8192 + (size_t)k * 16);
    #pragma unroll
    for (int q = 0; q < 4; q++) {
      float4 va = pa[q], vb = pb[q];
      a[q*4+0]=va.x*scale; a[q*4+1]=va.y*scale; a[q*4+2]=va.z*scale; a[q*4+3]=va.w*scale;
      b[q*4+0]=vb.x*scale; b[q*4+1]=vb.y*scale; b[q*4+2]=vb.z*scale; b[q*4+3]=vb.w*scale;
    }
    const float* Lf  = w + WR_L;
    const float* Lbf = w + WR_LB;
    #pragma unroll
    for (int t = 0; t < 16; t++) y[t] = a[t] + Lbf[t];
    #pragma unroll
    for (int cc = 0; cc < 16; cc++) {
      #pragma unroll
      for (int t = 0; t < 16; t++) y[t] += b[cc] * Lf[cc * 16 + t];
    }
  }
  {
    const float* V0t = w + WR_V0T; const float* c0f = w + WR_C0;
    for (int m = 0; m < 32; m++) {
      float s0 = c0f[2*m], s1 = c0f[2*m+1];
      #pragma unroll
      for (int t = 0; t < 16; t++) {
        s0 += y[t] * V0t[(2*m) * 16 + t];
        s1 += y[t] * V0t[(2*m+1) * 16 + t];
      }
      hbuf[m * 256 + tid] = pack2(fmaxf(s0, 0.f), fmaxf(s1, 0.f));
    }
  }
  #pragma unroll
  for (int lyr = 0; lyr < 2; lyr++) {
    const float* Vf = w + (lyr ? WR_V2 : WR_V1);
    const float* cf = w + (lyr ? WR_C2 : WR_C1);
    unsigned held[16];
    #pragma unroll
    for (int pass = 0; pass < 2; pass++) {
      float s[32];
      #pragma unroll
      for (int jj = 0; jj < 32; jj++) s[jj] = cf[pass * 32 + jj];
      for (int m = 0; m < 32; m++) {
        unsigned hu = hbuf[m * 256 + tid];
        float h0 = bflo(hu), h1 = bfhi(hu);
        #pragma unroll
        for (int jj = 0; jj < 32; jj++)
          s[jj] += h0 * Vf[(2*m) * 64 + pass*32 + jj] + h1 * Vf[(2*m+1) * 64 + pass*32 + jj];
      }
      if (pass == 0) {
        #pragma unroll
        for (int q = 0; q < 16; q++) held[q] = pack2(fmaxf(s[2*q], 0.f), fmaxf(s[2*q+1], 0.f));
      } else {
        #pragma unroll
        for (int q = 0; q < 16; q++) hbuf[q * 256 + tid] = held[q];
        #pragma unroll
        for (int q = 0; q < 16; q++) hbuf[(16 + q) * 256 + tid] = pack2(fmaxf(s[2*q], 0.f), fmaxf(s[2*q+1], 0.f));
      }
    }
  }
  float rr[16];
  {
    const float* V3f = w + WR_V3; const float* c3f = w + WR_C3;
    #pragma unroll
    for (int t = 0; t < 16; t++) rr[t] = c3f[t];
    for (int m = 0; m < 32; m++) {
      unsigned hu = hbuf[m * 256 + tid];
      float h0 = bflo(hu), h1 = bfhi(hu);
      #pragma unroll
      for (int t = 0; t < 16; t++)
        rr[t] += h0 * V3f[(2*m) * 16 + t] + h1 * V3f[(2*m+1) * 16 + t];
    }
  }
  size_t base = (size_t)i * 8192 + (size_t)k * 16;
  float mv[16];
  load16f(mtr, base, f32, mv);
  if (f32) {
    float4* op = (float4*)((float*)out + base);
    op[0] = make_float4(mv[0]+rr[0],  mv[1]+rr[1],  mv[2]+rr[2],  mv[3]+rr[3]);
    op[1] = make_float4(mv[4]+rr[4],  mv[5]+rr[5],  mv[6]+rr[6],  mv[7]+rr[7]);
    op[2] = make_float4(mv[8]+rr[8],  mv[9]+rr[9],  mv[10]+rr[10],mv[11]+rr[11]);
    op[3] = make_float4(mv[12]+rr[12],mv[13]+rr[13],mv[14]+rr[14],mv[15]+rr[15]);
  } else {
    unsigned pw[8];
    #pragma unroll
    for (int q = 0; q < 8; q++)
      pw[q] = pack2(mv[2*q] + rr[2*q], mv[2*q+1] + rr[2*q+1]);
    uint4* op = (uint4*)((__hip_bfloat16*)out + base);
    op[0] = make_uint4(pw[0], pw[1], pw[2], pw[3]);
    op[1] = make_uint4(pw[4], pw[5], pw[6], pw[7]);
  }
}

extern "C" void kernel_launch(void* const* d_in, const int* in_sizes, int n_in,
                              void* d_out, int out_size, void* d_ws, size_t ws_size,
                              hipStream_t stream)
{
  const void* mtr = d_in[0];
  const void* ea  = d_in[1];
  const int*  ei  = (const int*)d_in[2];

  float* ws    = (float*)d_ws;
  float* Fws   = ws + OFF_F;
  float* mtr1T = ws + OFF_MTR1;
  __hip_bfloat16* mtr1B = (__hip_bfloat16*)(ws + OFF_MTR1);
  float* w     = ws + OFF_W;
  int* offs    = (int*)(ws + OFF_OFFS);
  int* sorted  = (int*)(ws + OFF_SORTED);
  int* flag    = (int*)(ws + OFF_FLAG);
  __hip_bfloat16* mtrT = (__hip_bfloat16*)(ws + OFF_MTRT);
  int* offsP   = (int*)(ws + OFF_OFFSP);
  unsigned* packP = (unsigned*)(ws + OFF_PACKP);
  unsigned short* Fpack = (unsigned short*)(ws + OFF_FPACK);
  unsigned short* VP    = (unsigned short*)(ws + OFF_VPACK);

  if (ws_size >= WS_FULL2_BYTES) {
    prep_all<<<1573, 512, 0, stream>>>(
        mtr, ea, ei,
        d_in[3], d_in[4], d_in[5], d_in[6], d_in[7], d_in[8], d_in[9], d_in[10],
        d_in[11], d_in[12], d_in[13], d_in[14], d_in[15], d_in[16], d_in[17], d_in[18],
        d_in[19], d_in[20],
        flag, w, VP, offsP, packP, Fpack, mtrT);
    dim3 gmsg(512, 4);
    message_mfma2<<<gmsg, 256, 0, stream>>>(mtrT, Fpack, offsP, packP, mtr1B);
    final_mfma<<<1024, 512, 0, stream>>>(mtr, w, mtr1B, flag, VP, d_out);
  } else {
    prep_weights<<<32, 256, 0, stream>>>(d_in[3], d_in[4], d_in[5], d_in[6],
                                         d_in[7], d_in[8], d_in[9], d_in[10],
                                         d_in[11], d_in[12], d_in[13], d_in[14],
                                         d_in[15], d_in[16], d_in[17], d_in[18],
                                         d_in[19], d_in[20],
                                         (const unsigned short*)mtr, flag, w);
    build_bins_basic<<<1, 512, 0, stream>>>(ei, offs, sorted);
    edge_mlp_fb<<<EE / 4, 256, 0, stream>>>(ea, w, flag, Fws);
    dim3 gmsg(512, 2);
    message_kernel_direct<<<gmsg, 256, 0, stream>>>(mtr, ei, Fws, offs, sorted, flag, mtr1T);
    final_kernel_fb<<<1024, 256, 0, stream>>>(mtr, w, mtr1T, flag, d_out);
  }
}